// Round 9
// baseline (549.714 us; speedup 1.0000x reference)
//
#include <hip/hip_runtime.h>

#define CC 128
#define HH 128
#define WW 128
#define DH 64
#define DW 64
#define LTOT 4096          // DH*DW patches / fg positions
#define K0S 384            // 3*128 split-concat K for the pixel-pair GEMM
#define K2 2048            // CC*4*4
#define GK 4096            // GEMM2 full K
#define GKH 2048           // GEMM2 half K (split-K by 2)
#define SCALE_F 10.0f
#define IMG ((size_t)CC * HH * WW)
#define PSTR 4104          // padded S row stride (floats): 4 pad | 4096 | 4 pad; %4==0 keeps 16B align

typedef __attribute__((ext_vector_type(8))) short short8;
typedef __attribute__((ext_vector_type(4))) float f32x4;

// ---- pointer-pack structs (batch-merged prep via blockIdx.z) ----
struct Prep4 { const float* src[4]; unsigned short* dst[4]; float* ssq[4]; int lo[4]; };
struct PtrN2 { const float* ssq[2]; float* invn[2]; float* mmv[2]; };
struct PtrR2 { const float* src[2]; unsigned short* dst[2]; };

// ---- bf16 helpers (RNE) ----
__device__ __forceinline__ unsigned short f2bf(float x) {
    union { float f; unsigned u; } v; v.f = x;
    unsigned r = v.u + 0x7fffu + ((v.u >> 16) & 1u);
    return (unsigned short)(r >> 16);
}
__device__ __forceinline__ float bf2f(unsigned short b) {
    union { unsigned u; float f; } v; v.u = ((unsigned)b) << 16;
    return v.f;
}

// unaligned (4B-aligned) float4 load
__device__ __forceinline__ f32x4 ld4u(const float* p) {
    f32x4 r; __builtin_memcpy(&r, p, 16); return r;
}

#define GLDS16(g, l) __builtin_amdgcn_global_load_lds( \
    (const __attribute__((address_space(1))) void*)(g), \
    (__attribute__((address_space(3))) void*)(l), 16, 0, 0)

// ---------------- downsample (::2) + fp32->bf16 split + (for b) fused ssq reduce ----------------
// b gets [hi, lo, hi], f gets [hi, hi, lo]  =>  products sum to hi*hi + lo*hi + hi*lo
__global__ __launch_bounds__(128) void split_ds_kernel(Prep4 P) {
    __shared__ float partial[2];
    int z = blockIdx.z;
    const float* __restrict__ src = P.src[z];
    unsigned short* __restrict__ dst = P.dst[z];
    int lo_in_seg1 = P.lo[z];
    int n = blockIdx.x;          // 4096 pixels
    int c = threadIdx.x;         // 128 channels
    int ny = n >> 6, nx = n & 63;
    float v = src[((size_t)c * HH + 2 * ny) * WW + 2 * nx];
    unsigned short hi = f2bf(v);
    unsigned short lo = f2bf(v - bf2f(hi));
    unsigned short* drow = dst + (size_t)n * K0S;
    drow[c]       = hi;
    drow[128 + c] = lo_in_seg1 ? lo : hi;
    drow[256 + c] = lo_in_seg1 ? hi : lo;

    float* ssq = P.ssq[z];
    if (ssq) {                   // b images only: per-pixel channel sum of squares
        float s2 = v * v;
#pragma unroll
        for (int o = 32; o; o >>= 1) s2 += __shfl_xor(s2, o);
        if ((threadIdx.x & 63) == 0) partial[threadIdx.x >> 6] = s2;
        __syncthreads();
        if (threadIdx.x == 0) ssq[n] = partial[0] + partial[1];
    }
}

// ---------------- raw 4x4 stride-2 patches of full-res b, transposed: dst[m2][p] bf16 ----------------
// R8: thread owns a px-PAIR; interior threads cover both taps with one unaligned f32x4.
__global__ __launch_bounds__(256) void im2col_rawt_kernel(PtrR2 P) {
    int z = blockIdx.z;
    const float* __restrict__ src = P.src[z];
    unsigned short* __restrict__ dst = P.dst[z];
    int idx = blockIdx.x * 256 + threadIdx.x;     // m*2048 + py*32 + u
    int u  = idx & 31;                             // px pair index: px0 = 2u
    int py = (idx >> 5) & 63;
    int m  = idx >> 11;                            // (c,kd,ke)
    int ke = m & 3, kd = (m >> 2) & 3, c = m >> 4;
    int yy = 2 * py - 1 + kd;
    int xx0 = 4 * u - 1 + ke;                      // xx for px0; px1 uses xx0+2
    unsigned short o0 = 0, o1 = 0;
    if (yy >= 0 && yy < HH) {
        const float* row = src + ((size_t)c * HH + yy) * WW;
        if (u == 0 || u == 31) {                   // edges: scalar, bounds-checked
            if (xx0 >= 0 && xx0 < WW)         o0 = f2bf(row[xx0]);
            if (xx0 + 2 >= 0 && xx0 + 2 < WW) o1 = f2bf(row[xx0 + 2]);
        } else {                                   // interior: xx0 in [3,122]
            f32x4 w = ld4u(row + xx0);
            o0 = f2bf(w[0]); o1 = f2bf(w[2]);
        }
    }
    unsigned short* dp = dst + (size_t)m * LTOT + py * 64 + 2 * u;
    dp[0] = o0; dp[1] = o1;
}

// ---------------- patch inverse norm + mask gate ----------------
__global__ void norm_mm_kernel(PtrN2 P, const float* __restrict__ mask) {
    int z = blockIdx.z;
    const float* __restrict__ ssq = P.ssq[z];
    float* __restrict__ inv_norm = P.invn[z];
    float* __restrict__ mmv = P.mmv[z];
    int p = blockIdx.x * blockDim.x + threadIdx.x;     // 4096
    int px = p & 63, py = p >> 6;
    float s = 0.f, ms = 0.f;
    for (int di = -1; di <= 1; ++di)
        for (int dj = -1; dj <= 1; ++dj) {
            int y = py + di, x = px + dj;
            if (y >= 0 && y < DH && x >= 0 && x < DW) {
                s += ssq[y * 64 + x];
                ms += mask[(size_t)(2 * y) * WW + 2 * x];
            }
        }
    float n = sqrtf(s);
    if (n < 1e-4f) n = 1e-4f;
    inv_norm[p] = 1.f / n;
    mmv[p] = (ms == 0.f) ? 1.f : 0.f;
}

// ---------------- bf16 MFMA GEMM, BK=64, hoisted running pointers, XOR swizzle ----------------
// (kept for GEMM1: M=N=4096, K=384 — short-K, 1024 blocks)
__global__ __launch_bounds__(256) void gemm_mfma(
    const unsigned short* __restrict__ Aop, const unsigned short* __restrict__ Bop,
    float* __restrict__ C, int M, int N, int K)
{
    __shared__ short As[128 * 64];
    __shared__ short Bs[128 * 64];
    int tid = threadIdx.x;
    int wave = tid >> 6, lane = tid & 63;
    int wm = (wave >> 1) * 64;
    int wn = (wave & 1) * 64;
    int bm = blockIdx.y * 128, bn = blockIdx.x * 128;

    int rowS = wave * 32;              // wave stages rows [rowS, rowS+32)
    int lrow8 = lane >> 3;             // 0..7 (row within 8-row staging group)
    int gchunk = ((lane & 7) ^ lrow8) * 8;   // swizzled global k-offset (shorts)

    f32x4 acc[4][4] = {};

    int quad = lane >> 4;              // 0..3
    int r16 = lane & 15;
    int pc0 = ((quad)     ^ (r16 & 7)) * 8;  // physical chunk of k-slab 0
    int pc1 = ((4 + quad) ^ (r16 & 7)) * 8;  // physical chunk of k-slab 1

    const unsigned short* ap0 = Aop + (size_t)(bm + rowS +  0 + lrow8) * K + gchunk;
    const unsigned short* ap1 = Aop + (size_t)(bm + rowS +  8 + lrow8) * K + gchunk;
    const unsigned short* ap2 = Aop + (size_t)(bm + rowS + 16 + lrow8) * K + gchunk;
    const unsigned short* ap3 = Aop + (size_t)(bm + rowS + 24 + lrow8) * K + gchunk;
    const unsigned short* bp0 = Bop + (size_t)(bn + rowS +  0 + lrow8) * K + gchunk;
    const unsigned short* bp1 = Bop + (size_t)(bn + rowS +  8 + lrow8) * K + gchunk;
    const unsigned short* bp2 = Bop + (size_t)(bn + rowS + 16 + lrow8) * K + gchunk;
    const unsigned short* bp3 = Bop + (size_t)(bn + rowS + 24 + lrow8) * K + gchunk;
    short* lA = As + rowS * 64;        // wave-uniform LDS bases
    short* lB = Bs + rowS * 64;

    for (int k0 = 0; k0 < K; k0 += 64) {
        GLDS16(ap0, lA);            GLDS16(ap1, lA + 8 * 64);
        GLDS16(ap2, lA + 16 * 64);  GLDS16(ap3, lA + 24 * 64);
        GLDS16(bp0, lB);            GLDS16(bp1, lB + 8 * 64);
        GLDS16(bp2, lB + 16 * 64);  GLDS16(bp3, lB + 24 * 64);
        ap0 += 64; ap1 += 64; ap2 += 64; ap3 += 64;
        bp0 += 64; bp1 += 64; bp2 += 64; bp3 += 64;
        __syncthreads();

        short8 a0[4], b0[4], a1[4], b1[4];
#pragma unroll
        for (int i = 0; i < 4; ++i) {
            a0[i] = *(const short8*)&As[(wm + i * 16 + r16) * 64 + pc0];
            b0[i] = *(const short8*)&Bs[(wn + i * 16 + r16) * 64 + pc0];
            a1[i] = *(const short8*)&As[(wm + i * 16 + r16) * 64 + pc1];
            b1[i] = *(const short8*)&Bs[(wn + i * 16 + r16) * 64 + pc1];
        }
#pragma unroll
        for (int i = 0; i < 4; ++i)
#pragma unroll
            for (int j = 0; j < 4; ++j) {
                acc[i][j] = __builtin_amdgcn_mfma_f32_16x16x32_bf16(a0[i], b0[j], acc[i][j], 0, 0, 0);
                acc[i][j] = __builtin_amdgcn_mfma_f32_16x16x32_bf16(a1[i], b1[j], acc[i][j], 0, 0, 0);
            }
        __syncthreads();
    }

    int col = lane & 15, rq = (lane >> 4) * 4;
#pragma unroll
    for (int i = 0; i < 4; ++i) {
#pragma unroll
        for (int r = 0; r < 4; ++r) {
            int m = bm + wm + i * 16 + rq + r;
#pragma unroll
            for (int j = 0; j < 4; ++j)
                C[(size_t)m * N + bn + wn + j * 16 + col] = acc[i][j][r];
        }
    }
}

// ---------------- GEMM2: 256x256, split-K/2, ring-2 counted vmcnt + XCD panel swizzle (R7 body) ----------------
// R9: reverted R8's b-hoist (null/slightly negative). R7 body is gemm_k2's proven best
// (63.5 µs, FETCH 49 MB). Declared closed after R4/R6/R8 schedule nulls.
__global__ __launch_bounds__(512, 2) void gemm_k2(
    const unsigned short* __restrict__ Aop, const unsigned short* __restrict__ Bop,
    float* __restrict__ Cpart)
{
    constexpr int NT = 32;                    // GKH / 64
    constexpr int BUFS = 512 * 64;            // shorts per ring slot (64 KB)
    __shared__ short lds[2 * BUFS];           // 128 KB
    int flat = blockIdx.x;
    int xcd  = flat & 7;
    int slot = (flat >> 3) & 3;
    int bmId = flat >> 5;                     // 0..7
    int P    = slot * 8 + xcd;                // 0..31
    int bnId = P >> 1;                        // 0..15
    int ks   = P & 1;                         // K half
    int bm = bmId * 256, bn = bnId * 256;

    int tid = threadIdx.x;
    int wave = tid >> 6, lane = tid & 63;
    int wm = (wave >> 2) * 128;               // 0,128
    int wn = (wave & 3) * 64;                 // 0,64,128,192
    int lrow8 = lane >> 3;
    int gchunk = ((lane & 7) ^ lrow8) * 8;    // pre-swizzled global k-offset (shorts)
    int r16 = lane & 15, quad = lane >> 4;
    int pc0 = ((quad)     ^ (r16 & 7)) * 8;
    int pc1 = ((4 + quad) ^ (r16 & 7)) * 8;

    const size_t ko = (size_t)ks * GKH + gchunk;
    const unsigned short* ap0 = Aop + (size_t)(bm + wave * 32 +  0 + lrow8) * GK + ko;
    const unsigned short* ap1 = Aop + (size_t)(bm + wave * 32 +  8 + lrow8) * GK + ko;
    const unsigned short* ap2 = Aop + (size_t)(bm + wave * 32 + 16 + lrow8) * GK + ko;
    const unsigned short* ap3 = Aop + (size_t)(bm + wave * 32 + 24 + lrow8) * GK + ko;
    const unsigned short* bp0 = Bop + (size_t)(bn + wave * 32 +  0 + lrow8) * GK + ko;
    const unsigned short* bp1 = Bop + (size_t)(bn + wave * 32 +  8 + lrow8) * GK + ko;
    const unsigned short* bp2 = Bop + (size_t)(bn + wave * 32 + 16 + lrow8) * GK + ko;
    const unsigned short* bp3 = Bop + (size_t)(bn + wave * 32 + 24 + lrow8) * GK + ko;

    f32x4 acc[8][4] = {};

#define STAGE2(s) do { \
    short* la = lds + (s) * BUFS + (wave * 32) * 64; \
    short* lb = lds + (s) * BUFS + 256 * 64 + (wave * 32) * 64; \
    GLDS16(ap0, la);            GLDS16(ap1, la + 8 * 64); \
    GLDS16(ap2, la + 16 * 64);  GLDS16(ap3, la + 24 * 64); \
    GLDS16(bp0, lb);            GLDS16(bp1, lb + 8 * 64); \
    GLDS16(bp2, lb + 16 * 64);  GLDS16(bp3, lb + 24 * 64); \
    ap0 += 64; ap1 += 64; ap2 += 64; ap3 += 64; \
    bp0 += 64; bp1 += 64; bp2 += 64; bp3 += 64; } while (0)

    STAGE2(0); STAGE2(1);
    asm volatile("s_waitcnt vmcnt(8)" ::: "memory");
    __builtin_amdgcn_s_barrier();
    asm volatile("" ::: "memory");

    int buf = 0;
#pragma unroll 1
    for (int T = 0; T < NT; ++T) {
        const short* Ab = lds + buf * BUFS;
        const short* Bb = Ab + 256 * 64;
        short8 a0[8], a1[8], b0[4], b1[4];
#pragma unroll
        for (int j = 0; j < 4; ++j) {
            b0[j] = *(const short8*)&Bb[(wn + j * 16 + r16) * 64 + pc0];
            b1[j] = *(const short8*)&Bb[(wn + j * 16 + r16) * 64 + pc1];
        }
        a0[0] = *(const short8*)&Ab[(wm + r16) * 64 + pc0];
        a1[0] = *(const short8*)&Ab[(wm + r16) * 64 + pc1];
#pragma unroll
        for (int i = 0; i < 8; ++i) {
            if (i < 7) {
                a0[i + 1] = *(const short8*)&Ab[(wm + (i + 1) * 16 + r16) * 64 + pc0];
                a1[i + 1] = *(const short8*)&Ab[(wm + (i + 1) * 16 + r16) * 64 + pc1];
                asm volatile("s_waitcnt lgkmcnt(2)" ::: "memory");   // all but newest a-pair done
            } else {
                asm volatile("s_waitcnt lgkmcnt(0)" ::: "memory");
            }
            __builtin_amdgcn_sched_barrier(0);                       // rule 18: pin MFMA below wait
            __builtin_amdgcn_s_setprio(1);
#pragma unroll
            for (int j = 0; j < 4; ++j) {
                acc[i][j] = __builtin_amdgcn_mfma_f32_16x16x32_bf16(a0[i], b0[j], acc[i][j], 0, 0, 0);
                acc[i][j] = __builtin_amdgcn_mfma_f32_16x16x32_bf16(a1[i], b1[j], acc[i][j], 0, 0, 0);
            }
            __builtin_amdgcn_s_setprio(0);
        }
        asm volatile("s_waitcnt vmcnt(0)" ::: "memory");
        __builtin_amdgcn_s_barrier();
        asm volatile("" ::: "memory");
        if (T + 2 < NT) STAGE2(buf);
        buf ^= 1;
    }
#undef STAGE2

    float* Cout = Cpart + (size_t)ks * K2 * LTOT;
    int col = lane & 15, rq = (lane >> 4) * 4;
#pragma unroll
    for (int i = 0; i < 8; ++i) {
#pragma unroll
        for (int r = 0; r < 4; ++r) {
            int m = bm + wm + i * 16 + rq + r;
#pragma unroll
            for (int j = 0; j < 4; ++j)
                Cout[(size_t)m * LTOT + bn + wn + j * 16 + col] = acc[i][j][r];
        }
    }
}

// ---------------- 9-tap patch stencil, 4-q blocked: block owns q0..q0+3 ----------------
// R9: the 9 diagonal taps of 4 consecutive q touch 18 distinct C rows (q0+64du+s, s=-1..4)
// instead of 4x9=36 -> L2-side read traffic halves (576->288 MB/dispatch). Per-q (du,dv)
// visit order unchanged -> bit-identical accumulation. 1024 blocks, XCD swizzle on q-groups.
__global__ __launch_bounds__(256) void stencil_norm_kernel(
    const float* __restrict__ C, const float* __restrict__ invn,
    float* __restrict__ Sg)
{
    int blk = blockIdx.x;                    // 1024
    int gq = ((blk & 7) << 7) | (blk >> 3);  // XCD swizzle: 512 contiguous q per XCD
    int q0 = gq << 2;
    int t = threadIdx.x;
    int chunk = t >> 2;                      // py (uniform over the 16 cols)
    int lanebase = (t & 3) << 4;             // px of first col
    int p0 = t << 4;

    f32x4 acc[4][4];
#pragma unroll
    for (int qq = 0; qq < 4; ++qq)
#pragma unroll
        for (int g = 0; g < 4; ++g) { acc[qq][g][0] = acc[qq][g][1] = acc[qq][g][2] = acc[qq][g][3] = 0.f; }

#pragma unroll
    for (int du = -1; du <= 1; ++du) {
        if (chunk + du < 0 || chunk + du > 63) continue;   // py+du (thread-level, q-independent)
#pragma unroll
        for (int dv = -1; dv <= 1; ++dv) {
#pragma unroll
            for (int qq = 0; qq < 4; ++qq) {
                int q = q0 + qq;
                int qy = q >> 6, qx = q & 63;
                if (qy + du < 0 || qy + du > 63) continue;
                if (qx + dv < 0 || qx + dv > 63) continue;
                const float* rowp = C + (size_t)(q + 64 * du + dv) * LTOT + 64 * du + dv + p0;
#pragma unroll
                for (int g = 0; g < 4; ++g) {
                    f32x4 lv = ld4u(rowp + 4 * g);
                    if (dv == -1 && g == 0 && lanebase == 0)  lv[0] = 0.f;  // px+dv = -1
                    if (dv ==  1 && g == 3 && lanebase == 48) lv[3] = 0.f;  // px+dv = 64
                    acc[qq][g] += lv;
                }
            }
        }
    }
#pragma unroll
    for (int qq = 0; qq < 4; ++qq) {
        float* orow = Sg + (size_t)(q0 + qq) * PSTR;
#pragma unroll
        for (int g = 0; g < 4; ++g) {
            f32x4 iv = *(const f32x4*)(invn + p0 + 4 * g);
            *(f32x4*)(orow + p0 + 4 * g) = acc[qq][g] * iv;
        }
        // zero this row's column pads (reads touch cols -1 .. 4099)
        if (t == 0) { orow[-4] = orow[-3] = orow[-2] = orow[-1] = 0.f; }
        else if (t == 1) { orow[4096] = orow[4097] = orow[4098] = orow[4099] = 0.f; }
    }
    // zero guard rows -1 and 4096 (full padded rows)
    if (q0 == 0) {
        float* gr = Sg - 4 - PSTR;
        for (int k = t; k < PSTR; k += 256) gr[k] = 0.f;
    }
    if (q0 == 4092) {
        float* gr = Sg - 4 + (size_t)4096 * PSTR;
        for (int k = t; k < PSTR; k += 256) gr[k] = 0.f;
    }
}

// ---------------- fused (fuse2 o fuse1) stencil + row softmax + bf16, 2-q blocked ----------------
// R9: pair (q, q+64) -> swapped-space rows rbase, rbase+1; j-windows overlap: 4 distinct r2
// (12 physical row-reads) instead of 6 (18) -> L2 traffic x2/3, 2x per-thread loads in
// flight. Column map ccb is q-independent -> computed once per j, shared. Per-q j-order
// unchanged -> bit-identical. Two softmaxes share the same two __syncthreads.
__global__ __launch_bounds__(256) void fused_conv_softmax_kernel(
    const float* __restrict__ Sg, const float* __restrict__ mmv,
    unsigned short* __restrict__ S16)
{
    __shared__ float redmax[8];
    __shared__ float redsum[8];
    int blk = blockIdx.x;                       // 2048
    int h = ((blk & 7) << 8) | (blk >> 3);      // XCD swizzle on pair index
    int qx = h & 63, qy2 = h >> 6;              // qy2 0..31
    int qA = (2 * qy2) * 64 + qx;               // sub0 (qy even)
    int qB = qA + 64;                           // sub1 (qy odd)
    int t = threadIdx.x;
    int lane = t & 63, wid = t >> 6;
    int chunk = t >> 2;
    int lanebase = (t & 3) << 4;
    int c0 = t << 4;

    int rbA = ((qA & 63) << 6) | (qA >> 6);     // swap(qA)
    int rbB = rbA + 1;                          // swap(qB) (qy odd, no field overflow)

    f32x4 sA[4], sB[4];
#pragma unroll
    for (int g = 0; g < 4; ++g) {
        sA[g][0] = sA[g][1] = sA[g][2] = sA[g][3] = 0.f;
        sB[g][0] = sB[g][1] = sB[g][2] = sB[g][3] = 0.f;
    }

#pragma unroll
    for (int j = 0; j < 3; ++j) {               // d2 = j-1
        int cj = chunk + (j - 1);
        int ccb;
        if (cj < 0)       ccb = 4031 + lanebase;
        else if (cj > 63) ccb = lanebase + 1;
        else              ccb = (cj << 6) + lanebase;

        int r2A = rbA + (j - 1);
        if (r2A >= 0 && r2A < LTOT) {
            int rr = ((r2A & 63) << 6) | ((r2A >> 6) & 63);
            const float* pr = Sg + (size_t)rr * PSTR + ccb;
#pragma unroll
            for (int g = 0; g < 4; ++g) {
                const float* pg = pr + 4 * g;
                f32x4 tj = ld4u(pg - (PSTR + 1)) + ld4u(pg) + ld4u(pg + (PSTR + 1));
                if (j == 0 && g == 0 && t == 0)   tj[0] = 0.f;   // c=0 corner
                if (j == 2 && g == 3 && t == 255) tj[3] = 0.f;   // c=4095 corner
                sA[g] += tj;
            }
        }
        int r2B = rbB + (j - 1);
        if (r2B >= 0 && r2B < LTOT) {
            int rr = ((r2B & 63) << 6) | ((r2B >> 6) & 63);
            const float* pr = Sg + (size_t)rr * PSTR + ccb;
#pragma unroll
            for (int g = 0; g < 4; ++g) {
                const float* pg = pr + 4 * g;
                f32x4 tj = ld4u(pg - (PSTR + 1)) + ld4u(pg) + ld4u(pg + (PSTR + 1));
                if (j == 0 && g == 0 && t == 0)   tj[0] = 0.f;
                if (j == 2 && g == 3 && t == 255) tj[3] = 0.f;
                sB[g] += tj;
            }
        }
    }

    float vA[16], vB[16];
#pragma unroll
    for (int g = 0; g < 4; ++g) {
        f32x4 m4 = *(const f32x4*)(mmv + c0 + 4 * g);
#pragma unroll
        for (int e = 0; e < 4; ++e) {
            vA[4 * g + e] = sA[g][e] * m4[e] * SCALE_F;
            vB[4 * g + e] = sB[g][e] * m4[e] * SCALE_F;
        }
    }
#pragma unroll
    for (int k = 0; k < 16; ++k) { asm volatile("" : "+v"(vA[k])); asm volatile("" : "+v"(vB[k])); }

    float mxA = vA[0], mxB = vB[0];
#pragma unroll
    for (int i = 1; i < 16; ++i) { mxA = fmaxf(mxA, vA[i]); mxB = fmaxf(mxB, vB[i]); }
#pragma unroll
    for (int o = 32; o; o >>= 1) { mxA = fmaxf(mxA, __shfl_xor(mxA, o)); mxB = fmaxf(mxB, __shfl_xor(mxB, o)); }
    if (lane == 0) { redmax[wid] = mxA; redmax[4 + wid] = mxB; }
    __syncthreads();
    float gmxA = fmaxf(fmaxf(redmax[0], redmax[1]), fmaxf(redmax[2], redmax[3]));
    float gmxB = fmaxf(fmaxf(redmax[4], redmax[5]), fmaxf(redmax[6], redmax[7]));

    float suA = 0.f, suB = 0.f;
#pragma unroll
    for (int i = 0; i < 16; ++i) {
        vA[i] = __expf(vA[i] - gmxA); suA += vA[i];
        vB[i] = __expf(vB[i] - gmxB); suB += vB[i];
    }
#pragma unroll
    for (int o = 32; o; o >>= 1) { suA += __shfl_xor(suA, o); suB += __shfl_xor(suB, o); }
    if (lane == 0) { redsum[wid] = suA; redsum[4 + wid] = suB; }
    __syncthreads();
    float invA = 1.f / (redsum[0] + redsum[1] + redsum[2] + redsum[3]);
    float invB = 1.f / (redsum[4] + redsum[5] + redsum[6] + redsum[7]);

    unsigned short* orowA = S16 + (size_t)qA * LTOT + c0;
    unsigned short* orowB = S16 + (size_t)qB * LTOT + c0;
    short8 hA0, hA1, hB0, hB1;
#pragma unroll
    for (int e = 0; e < 8; ++e) {
        float m0 = mmv[c0 + e], m1 = mmv[c0 + 8 + e];
        hA0[e] = (short)f2bf(vA[e]     * invA * m0);
        hA1[e] = (short)f2bf(vA[8 + e] * invA * m1);
        hB0[e] = (short)f2bf(vB[e]     * invB * m0);
        hB1[e] = (short)f2bf(vB[8 + e] * invB * m1);
    }
    *(short8*)orowA = hA0; *(short8*)(orowA + 8) = hA1;
    *(short8*)orowB = hB0; *(short8*)(orowB + 8) = hB1;
}

// ---------------- overlap-add of weighted 4x4 patches (stride 2), /4 ----------------
// C2t is TRANSPOSED and SPLIT-K: two partials [m2][q]; taps contiguous across threads (x->ox).
__global__ void output_kernel(const float* __restrict__ C2t, float* __restrict__ out) {
    const float* __restrict__ P1 = C2t + (size_t)K2 * LTOT;
    int idx = blockIdx.x * blockDim.x + threadIdx.x;   // CC*HH*WW
    int x = idx & 127;
    int y = (idx >> 7) & 127;
    int c = idx >> 14;
    int oylo = max(0, (y - 1) >> 1), oyhi = min(63, (y + 1) >> 1);
    int oxlo = max(0, (x - 1) >> 1), oxhi = min(63, (x + 1) >> 1);
    float s = 0.f;
    for (int oy = oylo; oy <= oyhi; ++oy)
        for (int ox = oxlo; ox <= oxhi; ++ox) {
            int kd = y - 2 * oy + 1;
            int ke = x - 2 * ox + 1;
            size_t off = (size_t)(c * 16 + kd * 4 + ke) * LTOT + oy * 64 + ox;
            s += C2t[off] + P1[off];
        }
    out[idx] = s * 0.25f;
}

extern "C" void kernel_launch(void* const* d_in, const int* in_sizes, int n_in,
                              void* d_out, int out_size, void* d_ws, size_t ws_size,
                              hipStream_t stream) {
    (void)in_sizes; (void)n_in; (void)out_size; (void)ws_size;
    const float* f    = (const float*)d_in[0];
    const float* b    = (const float*)d_in[1];
    const float* mask = (const float*)d_in[2];
    float* out = (float*)d_out;

    const size_t SZ_MAT  = (size_t)LTOT * LTOT * 4;        // 64 MB
    const size_t SZ_SPAD = (size_t)PSTR * 4098 * 4;        // 67.3 MB padded S (guards + col pads)
    const size_t SZ_WR   = (size_t)K2 * LTOT * 2;          // 16 MB
    const size_t SZ_SP   = (size_t)LTOT * K0S * 2;         // 3 MB
    const size_t SZ_V    = (size_t)LTOT * 4;

    auto pad = [](size_t n) { return (n + 255) & ~(size_t)255; };
    char* p = (char*)d_ws;
    auto take = [&](size_t n) -> void* { void* r = (void*)p; p += pad(n); return r; };

    // footprint: 0.25K guard + 64 + 67.3 + 16 (single W) + 4*3 + small ~= 160 MB (< proven 172)
    take(256);                                     // guard: stencil corner reads C[-1]
    float* Buf1 = (float*)take(SZ_MAT);            // Cpix -> S16 (lower 32 MB)
    float* Spad = (float*)take(SZ_SPAD);           // padded S -> C2t partials (lower 64 MB)
    unsigned short* W = (unsigned short*)take(SZ_WR);   // per-batch raw patches (im2col in loop)
    unsigned short* Bsp0 = (unsigned short*)take(SZ_SP);
    unsigned short* Fsp0 = (unsigned short*)take(SZ_SP);
    unsigned short* Bsp1 = (unsigned short*)take(SZ_SP);
    unsigned short* Fsp1 = (unsigned short*)take(SZ_SP);
    float* ssq0 = (float*)take(SZ_V);  float* ssq1 = (float*)take(SZ_V);
    float* invn0 = (float*)take(SZ_V); float* invn1 = (float*)take(SZ_V);
    float* mmv0 = (float*)take(SZ_V);  float* mmv1 = (float*)take(SZ_V);

    const float* f0 = f,  *b0 = b;
    const float* f1 = f + IMG, *b1 = b + IMG;

    float* Sg = Spad + PSTR + 4;                   // padded S row 0, col 0
    unsigned short* S16 = (unsigned short*)Buf1;   // 32 MB, after Cpix dead
    float* C2t = Spad;                             // 2 x 32 MB partials, after padded S dead

    // ---- merged prep (both batches); ssq fused into the b split passes ----
    Prep4 P{{b0, f0, b1, f1}, {Bsp0, Fsp0, Bsp1, Fsp1},
            {ssq0, nullptr, ssq1, nullptr}, {1, 0, 1, 0}};
    split_ds_kernel<<<dim3(LTOT, 1, 4), 128, 0, stream>>>(P);
    PtrN2 nm{{ssq0, ssq1}, {invn0, invn1}, {mmv0, mmv1}};
    norm_mm_kernel<<<dim3(16, 1, 2), 256, 0, stream>>>(nm, mask);

    // ---- per-batch pipeline ----
    for (int bi = 0; bi < 2; ++bi) {
        const unsigned short* Fsp = bi ? Fsp1 : Fsp0;
        const unsigned short* Bsp = bi ? Bsp1 : Bsp0;
        const float* invn = bi ? invn1 : invn0;
        const float* mmv  = bi ? mmv1 : mmv0;

        // raw 4x4 patches for this batch only (W reused across batches); px-pair threads
        PtrR2 rw{{bi ? b1 : b0, nullptr}, {W, nullptr}};
        im2col_rawt_kernel<<<dim3((size_t)K2 * LTOT / 2 / 256, 1, 1), 256, 0, stream>>>(rw);

        // Cpix[q][p] = sum_c fd[c][q]*bd[c][p]   (split-concat fp32-accurate, K=384)
        gemm_mfma<<<dim3(32, 32), 256, 0, stream>>>(Fsp, Bsp, Buf1, LTOT, LTOT, K0S);

        // patch inner products: 9-tap diagonal stencil + invn column scale -> padded S (4-q blocks)
        stencil_norm_kernel<<<1024, 256, 0, stream>>>(Buf1, invn, Sg);

        // fused (fuse2 o fuse1) + softmax + bf16 cast  (2-q blocks; Cpix dead -> S16 in Buf1)
        fused_conv_softmax_kernel<<<2048, 256, 0, stream>>>(Sg, mmv, S16);

        // TRANSPOSED GEMM2 (ring-2 + XCD grouping, R7 body): C2t_ks[m2][q] = sum_p W[m2][p]*S16[q][p]
        gemm_k2<<<256, 512, 0, stream>>>(W, S16, C2t);

        output_kernel<<<CC * HH * WW / 256, 256, 0, stream>>>(C2t, out + (size_t)bi * IMG);
    }
}

// Round 10
// 501.027 us; speedup vs baseline: 1.0972x; 1.0972x over previous
//
#include <hip/hip_runtime.h>

#define CC 128
#define HH 128
#define WW 128
#define DH 64
#define DW 64
#define LTOT 4096          // DH*DW patches / fg positions
#define K0S 384            // 3*128 split-concat K for the pixel-pair GEMM
#define K2 2048            // CC*4*4
#define GK 4096            // GEMM2 full K
#define GKH 2048           // GEMM2 half K (split-K by 2)
#define SCALE_F 10.0f
#define IMG ((size_t)CC * HH * WW)
#define PSTR 4104          // padded S row stride (floats): 4 pad | 4096 | 4 pad; %4==0 keeps 16B align

typedef __attribute__((ext_vector_type(8))) short short8;
typedef __attribute__((ext_vector_type(4))) float f32x4;

// ---- pointer-pack structs (batch-merged prep via blockIdx.z) ----
struct Prep4 { const float* src[4]; unsigned short* dst[4]; float* ssq[4]; int lo[4]; };
struct PtrN2 { const float* ssq[2]; float* invn[2]; float* mmv[2]; };
struct PtrR2 { const float* src[2]; unsigned short* dst[2]; };

// ---- bf16 helpers (RNE) ----
__device__ __forceinline__ unsigned short f2bf(float x) {
    union { float f; unsigned u; } v; v.f = x;
    unsigned r = v.u + 0x7fffu + ((v.u >> 16) & 1u);
    return (unsigned short)(r >> 16);
}
__device__ __forceinline__ float bf2f(unsigned short b) {
    union { unsigned u; float f; } v; v.u = ((unsigned)b) << 16;
    return v.f;
}

// unaligned (4B-aligned) float4 load
__device__ __forceinline__ f32x4 ld4u(const float* p) {
    f32x4 r; __builtin_memcpy(&r, p, 16); return r;
}

#define GLDS16(g, l) __builtin_amdgcn_global_load_lds( \
    (const __attribute__((address_space(1))) void*)(g), \
    (__attribute__((address_space(3))) void*)(l), 16, 0, 0)

// ---------------- downsample (::2) + fp32->bf16 split + (for b) fused ssq reduce ----------------
// b gets [hi, lo, hi], f gets [hi, hi, lo]  =>  products sum to hi*hi + lo*hi + hi*lo
__global__ __launch_bounds__(128) void split_ds_kernel(Prep4 P) {
    __shared__ float partial[2];
    int z = blockIdx.z;
    const float* __restrict__ src = P.src[z];
    unsigned short* __restrict__ dst = P.dst[z];
    int lo_in_seg1 = P.lo[z];
    int n = blockIdx.x;          // 4096 pixels
    int c = threadIdx.x;         // 128 channels
    int ny = n >> 6, nx = n & 63;
    float v = src[((size_t)c * HH + 2 * ny) * WW + 2 * nx];
    unsigned short hi = f2bf(v);
    unsigned short lo = f2bf(v - bf2f(hi));
    unsigned short* drow = dst + (size_t)n * K0S;
    drow[c]       = hi;
    drow[128 + c] = lo_in_seg1 ? lo : hi;
    drow[256 + c] = lo_in_seg1 ? hi : lo;

    float* ssq = P.ssq[z];
    if (ssq) {                   // b images only: per-pixel channel sum of squares
        float s2 = v * v;
#pragma unroll
        for (int o = 32; o; o >>= 1) s2 += __shfl_xor(s2, o);
        if ((threadIdx.x & 63) == 0) partial[threadIdx.x >> 6] = s2;
        __syncthreads();
        if (threadIdx.x == 0) ssq[n] = partial[0] + partial[1];
    }
}

// ---------------- raw 4x4 stride-2 patches of full-res b, transposed: dst[m2][p] bf16 ----------------
// R8: thread owns a px-PAIR; interior threads cover both taps with one unaligned f32x4.
__global__ __launch_bounds__(256) void im2col_rawt_kernel(PtrR2 P) {
    int z = blockIdx.z;
    const float* __restrict__ src = P.src[z];
    unsigned short* __restrict__ dst = P.dst[z];
    int idx = blockIdx.x * 256 + threadIdx.x;     // m*2048 + py*32 + u
    int u  = idx & 31;                             // px pair index: px0 = 2u
    int py = (idx >> 5) & 63;
    int m  = idx >> 11;                            // (c,kd,ke)
    int ke = m & 3, kd = (m >> 2) & 3, c = m >> 4;
    int yy = 2 * py - 1 + kd;
    int xx0 = 4 * u - 1 + ke;                      // xx for px0; px1 uses xx0+2
    unsigned short o0 = 0, o1 = 0;
    if (yy >= 0 && yy < HH) {
        const float* row = src + ((size_t)c * HH + yy) * WW;
        if (u == 0 || u == 31) {                   // edges: scalar, bounds-checked
            if (xx0 >= 0 && xx0 < WW)         o0 = f2bf(row[xx0]);
            if (xx0 + 2 >= 0 && xx0 + 2 < WW) o1 = f2bf(row[xx0 + 2]);
        } else {                                   // interior: xx0 in [3,122]
            f32x4 w = ld4u(row + xx0);
            o0 = f2bf(w[0]); o1 = f2bf(w[2]);
        }
    }
    unsigned short* dp = dst + (size_t)m * LTOT + py * 64 + 2 * u;
    dp[0] = o0; dp[1] = o1;
}

// ---------------- patch inverse norm + mask gate ----------------
__global__ void norm_mm_kernel(PtrN2 P, const float* __restrict__ mask) {
    int z = blockIdx.z;
    const float* __restrict__ ssq = P.ssq[z];
    float* __restrict__ inv_norm = P.invn[z];
    float* __restrict__ mmv = P.mmv[z];
    int p = blockIdx.x * blockDim.x + threadIdx.x;     // 4096
    int px = p & 63, py = p >> 6;
    float s = 0.f, ms = 0.f;
    for (int di = -1; di <= 1; ++di)
        for (int dj = -1; dj <= 1; ++dj) {
            int y = py + di, x = px + dj;
            if (y >= 0 && y < DH && x >= 0 && x < DW) {
                s += ssq[y * 64 + x];
                ms += mask[(size_t)(2 * y) * WW + 2 * x];
            }
        }
    float n = sqrtf(s);
    if (n < 1e-4f) n = 1e-4f;
    inv_norm[p] = 1.f / n;
    mmv[p] = (ms == 0.f) ? 1.f : 0.f;
}

// ---------------- bf16 MFMA GEMM, BK=64, hoisted running pointers, XOR swizzle ----------------
// (kept for GEMM1: M=N=4096, K=384 — short-K, 1024 blocks)
__global__ __launch_bounds__(256) void gemm_mfma(
    const unsigned short* __restrict__ Aop, const unsigned short* __restrict__ Bop,
    float* __restrict__ C, int M, int N, int K)
{
    __shared__ short As[128 * 64];
    __shared__ short Bs[128 * 64];
    int tid = threadIdx.x;
    int wave = tid >> 6, lane = tid & 63;
    int wm = (wave >> 1) * 64;
    int wn = (wave & 1) * 64;
    int bm = blockIdx.y * 128, bn = blockIdx.x * 128;

    int rowS = wave * 32;              // wave stages rows [rowS, rowS+32)
    int lrow8 = lane >> 3;             // 0..7 (row within 8-row staging group)
    int gchunk = ((lane & 7) ^ lrow8) * 8;   // swizzled global k-offset (shorts)

    f32x4 acc[4][4] = {};

    int quad = lane >> 4;              // 0..3
    int r16 = lane & 15;
    int pc0 = ((quad)     ^ (r16 & 7)) * 8;  // physical chunk of k-slab 0
    int pc1 = ((4 + quad) ^ (r16 & 7)) * 8;  // physical chunk of k-slab 1

    const unsigned short* ap0 = Aop + (size_t)(bm + rowS +  0 + lrow8) * K + gchunk;
    const unsigned short* ap1 = Aop + (size_t)(bm + rowS +  8 + lrow8) * K + gchunk;
    const unsigned short* ap2 = Aop + (size_t)(bm + rowS + 16 + lrow8) * K + gchunk;
    const unsigned short* ap3 = Aop + (size_t)(bm + rowS + 24 + lrow8) * K + gchunk;
    const unsigned short* bp0 = Bop + (size_t)(bn + rowS +  0 + lrow8) * K + gchunk;
    const unsigned short* bp1 = Bop + (size_t)(bn + rowS +  8 + lrow8) * K + gchunk;
    const unsigned short* bp2 = Bop + (size_t)(bn + rowS + 16 + lrow8) * K + gchunk;
    const unsigned short* bp3 = Bop + (size_t)(bn + rowS + 24 + lrow8) * K + gchunk;
    short* lA = As + rowS * 64;        // wave-uniform LDS bases
    short* lB = Bs + rowS * 64;

    for (int k0 = 0; k0 < K; k0 += 64) {
        GLDS16(ap0, lA);            GLDS16(ap1, lA + 8 * 64);
        GLDS16(ap2, lA + 16 * 64);  GLDS16(ap3, lA + 24 * 64);
        GLDS16(bp0, lB);            GLDS16(bp1, lB + 8 * 64);
        GLDS16(bp2, lB + 16 * 64);  GLDS16(bp3, lB + 24 * 64);
        ap0 += 64; ap1 += 64; ap2 += 64; ap3 += 64;
        bp0 += 64; bp1 += 64; bp2 += 64; bp3 += 64;
        __syncthreads();

        short8 a0[4], b0[4], a1[4], b1[4];
#pragma unroll
        for (int i = 0; i < 4; ++i) {
            a0[i] = *(const short8*)&As[(wm + i * 16 + r16) * 64 + pc0];
            b0[i] = *(const short8*)&Bs[(wn + i * 16 + r16) * 64 + pc0];
            a1[i] = *(const short8*)&As[(wm + i * 16 + r16) * 64 + pc1];
            b1[i] = *(const short8*)&Bs[(wn + i * 16 + r16) * 64 + pc1];
        }
#pragma unroll
        for (int i = 0; i < 4; ++i)
#pragma unroll
            for (int j = 0; j < 4; ++j) {
                acc[i][j] = __builtin_amdgcn_mfma_f32_16x16x32_bf16(a0[i], b0[j], acc[i][j], 0, 0, 0);
                acc[i][j] = __builtin_amdgcn_mfma_f32_16x16x32_bf16(a1[i], b1[j], acc[i][j], 0, 0, 0);
            }
        __syncthreads();
    }

    int col = lane & 15, rq = (lane >> 4) * 4;
#pragma unroll
    for (int i = 0; i < 4; ++i) {
#pragma unroll
        for (int r = 0; r < 4; ++r) {
            int m = bm + wm + i * 16 + rq + r;
#pragma unroll
            for (int j = 0; j < 4; ++j)
                C[(size_t)m * N + bn + wn + j * 16 + col] = acc[i][j][r];
        }
    }
}

// ---------------- GEMM2: 256x256, split-K/2, ring-2 counted vmcnt + XCD panel swizzle (R7 body) ----------------
// Proven best (63.5 µs, FETCH 49 MB). Closed after R4/R6/R8 schedule nulls.
__global__ __launch_bounds__(512, 2) void gemm_k2(
    const unsigned short* __restrict__ Aop, const unsigned short* __restrict__ Bop,
    float* __restrict__ Cpart)
{
    constexpr int NT = 32;                    // GKH / 64
    constexpr int BUFS = 512 * 64;            // shorts per ring slot (64 KB)
    __shared__ short lds[2 * BUFS];           // 128 KB
    int flat = blockIdx.x;
    int xcd  = flat & 7;
    int slot = (flat >> 3) & 3;
    int bmId = flat >> 5;                     // 0..7
    int P    = slot * 8 + xcd;                // 0..31
    int bnId = P >> 1;                        // 0..15
    int ks   = P & 1;                         // K half
    int bm = bmId * 256, bn = bnId * 256;

    int tid = threadIdx.x;
    int wave = tid >> 6, lane = tid & 63;
    int wm = (wave >> 2) * 128;               // 0,128
    int wn = (wave & 3) * 64;                 // 0,64,128,192
    int lrow8 = lane >> 3;
    int gchunk = ((lane & 7) ^ lrow8) * 8;    // pre-swizzled global k-offset (shorts)
    int r16 = lane & 15, quad = lane >> 4;
    int pc0 = ((quad)     ^ (r16 & 7)) * 8;
    int pc1 = ((4 + quad) ^ (r16 & 7)) * 8;

    const size_t ko = (size_t)ks * GKH + gchunk;
    const unsigned short* ap0 = Aop + (size_t)(bm + wave * 32 +  0 + lrow8) * GK + ko;
    const unsigned short* ap1 = Aop + (size_t)(bm + wave * 32 +  8 + lrow8) * GK + ko;
    const unsigned short* ap2 = Aop + (size_t)(bm + wave * 32 + 16 + lrow8) * GK + ko;
    const unsigned short* ap3 = Aop + (size_t)(bm + wave * 32 + 24 + lrow8) * GK + ko;
    const unsigned short* bp0 = Bop + (size_t)(bn + wave * 32 +  0 + lrow8) * GK + ko;
    const unsigned short* bp1 = Bop + (size_t)(bn + wave * 32 +  8 + lrow8) * GK + ko;
    const unsigned short* bp2 = Bop + (size_t)(bn + wave * 32 + 16 + lrow8) * GK + ko;
    const unsigned short* bp3 = Bop + (size_t)(bn + wave * 32 + 24 + lrow8) * GK + ko;

    f32x4 acc[8][4] = {};

#define STAGE2(s) do { \
    short* la = lds + (s) * BUFS + (wave * 32) * 64; \
    short* lb = lds + (s) * BUFS + 256 * 64 + (wave * 32) * 64; \
    GLDS16(ap0, la);            GLDS16(ap1, la + 8 * 64); \
    GLDS16(ap2, la + 16 * 64);  GLDS16(ap3, la + 24 * 64); \
    GLDS16(bp0, lb);            GLDS16(bp1, lb + 8 * 64); \
    GLDS16(bp2, lb + 16 * 64);  GLDS16(bp3, lb + 24 * 64); \
    ap0 += 64; ap1 += 64; ap2 += 64; ap3 += 64; \
    bp0 += 64; bp1 += 64; bp2 += 64; bp3 += 64; } while (0)

    STAGE2(0); STAGE2(1);
    asm volatile("s_waitcnt vmcnt(8)" ::: "memory");
    __builtin_amdgcn_s_barrier();
    asm volatile("" ::: "memory");

    int buf = 0;
#pragma unroll 1
    for (int T = 0; T < NT; ++T) {
        const short* Ab = lds + buf * BUFS;
        const short* Bb = Ab + 256 * 64;
        short8 a0[8], a1[8], b0[4], b1[4];
#pragma unroll
        for (int j = 0; j < 4; ++j) {
            b0[j] = *(const short8*)&Bb[(wn + j * 16 + r16) * 64 + pc0];
            b1[j] = *(const short8*)&Bb[(wn + j * 16 + r16) * 64 + pc1];
        }
        a0[0] = *(const short8*)&Ab[(wm + r16) * 64 + pc0];
        a1[0] = *(const short8*)&Ab[(wm + r16) * 64 + pc1];
#pragma unroll
        for (int i = 0; i < 8; ++i) {
            if (i < 7) {
                a0[i + 1] = *(const short8*)&Ab[(wm + (i + 1) * 16 + r16) * 64 + pc0];
                a1[i + 1] = *(const short8*)&Ab[(wm + (i + 1) * 16 + r16) * 64 + pc1];
                asm volatile("s_waitcnt lgkmcnt(2)" ::: "memory");   // all but newest a-pair done
            } else {
                asm volatile("s_waitcnt lgkmcnt(0)" ::: "memory");
            }
            __builtin_amdgcn_sched_barrier(0);                       // rule 18: pin MFMA below wait
            __builtin_amdgcn_s_setprio(1);
#pragma unroll
            for (int j = 0; j < 4; ++j) {
                acc[i][j] = __builtin_amdgcn_mfma_f32_16x16x32_bf16(a0[i], b0[j], acc[i][j], 0, 0, 0);
                acc[i][j] = __builtin_amdgcn_mfma_f32_16x16x32_bf16(a1[i], b1[j], acc[i][j], 0, 0, 0);
            }
            __builtin_amdgcn_s_setprio(0);
        }
        asm volatile("s_waitcnt vmcnt(0)" ::: "memory");
        __builtin_amdgcn_s_barrier();
        asm volatile("" ::: "memory");
        if (T + 2 < NT) STAGE2(buf);
        buf ^= 1;
    }
#undef STAGE2

    float* Cout = Cpart + (size_t)ks * K2 * LTOT;
    int col = lane & 15, rq = (lane >> 4) * 4;
#pragma unroll
    for (int i = 0; i < 8; ++i) {
#pragma unroll
        for (int r = 0; r < 4; ++r) {
            int m = bm + wm + i * 16 + rq + r;
#pragma unroll
            for (int j = 0; j < 4; ++j)
                Cout[(size_t)m * LTOT + bn + wn + j * 16 + col] = acc[i][j][r];
        }
    }
}

// ---------------- 9-tap patch stencil, VECTORIZED (R2 proven body): thread t owns 16 cols ----------------
// R10: REVERTED R9's 4-q blocking — it thrashed L1/L2 (36 read streams/block): FETCH
// 187 MB (3x the matrix), occupancy 32%, 79 µs. Single-q version keeps 9 sequential
// row-streams L2-resident.
__global__ __launch_bounds__(256) void stencil_norm_kernel(
    const float* __restrict__ C, const float* __restrict__ invn,
    float* __restrict__ Sg)
{
    int blk = blockIdx.x;
    int q = ((blk & 7) << 9) | (blk >> 3);   // XCD swizzle: contiguous 512-q per XCD
    int t = threadIdx.x;
    int qy = q >> 6, qx = q & 63;
    int chunk = t >> 2;                      // py (uniform over the 16 cols)
    int lanebase = (t & 3) << 4;             // px of first col
    int p0 = t << 4;

    f32x4 acc[4];
#pragma unroll
    for (int g = 0; g < 4; ++g) { acc[g][0] = acc[g][1] = acc[g][2] = acc[g][3] = 0.f; }

#pragma unroll
    for (int du = -1; du <= 1; ++du) {
        if (qy + du < 0 || qy + du > 63) continue;
        if (chunk + du < 0 || chunk + du > 63) continue;   // py+du (uniform)
#pragma unroll
        for (int dv = -1; dv <= 1; ++dv) {
            if (qx + dv < 0 || qx + dv > 63) continue;
            const float* rowp = C + (size_t)(q + 64 * du + dv) * LTOT + 64 * du + dv + p0;
#pragma unroll
            for (int g = 0; g < 4; ++g) {
                f32x4 lv = ld4u(rowp + 4 * g);
                if (dv == -1 && g == 0 && lanebase == 0)  lv[0] = 0.f;  // px+dv = -1
                if (dv ==  1 && g == 3 && lanebase == 48) lv[3] = 0.f;  // px+dv = 64
                acc[g] += lv;
            }
        }
    }
    float* orow = Sg + (size_t)q * PSTR;
#pragma unroll
    for (int g = 0; g < 4; ++g) {
        f32x4 iv = *(const f32x4*)(invn + p0 + 4 * g);
        *(f32x4*)(orow + p0 + 4 * g) = acc[g] * iv;
    }
    // zero this row's column pads (reads touch cols -1 .. 4099)
    if (t == 0) { orow[-4] = orow[-3] = orow[-2] = orow[-1] = 0.f; }
    else if (t == 1) { orow[4096] = orow[4097] = orow[4098] = orow[4099] = 0.f; }
    // zero guard rows -1 and 4096 (full padded rows)
    if (q == 0) {
        float* gr = Sg - 4 - PSTR;
        for (int k = t; k < PSTR; k += 256) gr[k] = 0.f;
    }
    if (q == 4095) {
        float* gr = Sg - 4 + (size_t)4096 * PSTR;
        for (int k = t; k < PSTR; k += 256) gr[k] = 0.f;
    }
}

// ---------------- fused (fuse2 o fuse1) stencil + row softmax + bf16, 2-q blocked (R9 win, kept) ----------------
// Pair (q, q+64): swapped-space rows rbase, rbase+1 overlap j-windows -> 4 distinct r2 rows
// (12 physical row-reads) instead of 6 (18) -> L2 traffic x2/3 + 2x loads in flight.
// R9 inference: this saved ~35-40 µs total (stencil regression accounted for more than the
// net delta). Per-q j-order unchanged -> bit-identical.
__global__ __launch_bounds__(256) void fused_conv_softmax_kernel(
    const float* __restrict__ Sg, const float* __restrict__ mmv,
    unsigned short* __restrict__ S16)
{
    __shared__ float redmax[8];
    __shared__ float redsum[8];
    int blk = blockIdx.x;                       // 2048
    int h = ((blk & 7) << 8) | (blk >> 3);      // XCD swizzle on pair index
    int qx = h & 63, qy2 = h >> 6;              // qy2 0..31
    int qA = (2 * qy2) * 64 + qx;               // sub0 (qy even)
    int qB = qA + 64;                           // sub1 (qy odd)
    int t = threadIdx.x;
    int lane = t & 63, wid = t >> 6;
    int chunk = t >> 2;
    int lanebase = (t & 3) << 4;
    int c0 = t << 4;

    int rbA = ((qA & 63) << 6) | (qA >> 6);     // swap(qA)
    int rbB = rbA + 1;                          // swap(qB) (qy odd, no field overflow)

    f32x4 sA[4], sB[4];
#pragma unroll
    for (int g = 0; g < 4; ++g) {
        sA[g][0] = sA[g][1] = sA[g][2] = sA[g][3] = 0.f;
        sB[g][0] = sB[g][1] = sB[g][2] = sB[g][3] = 0.f;
    }

#pragma unroll
    for (int j = 0; j < 3; ++j) {               // d2 = j-1
        int cj = chunk + (j - 1);
        int ccb;
        if (cj < 0)       ccb = 4031 + lanebase;
        else if (cj > 63) ccb = lanebase + 1;
        else              ccb = (cj << 6) + lanebase;

        int r2A = rbA + (j - 1);
        if (r2A >= 0 && r2A < LTOT) {
            int rr = ((r2A & 63) << 6) | ((r2A >> 6) & 63);
            const float* pr = Sg + (size_t)rr * PSTR + ccb;
#pragma unroll
            for (int g = 0; g < 4; ++g) {
                const float* pg = pr + 4 * g;
                f32x4 tj = ld4u(pg - (PSTR + 1)) + ld4u(pg) + ld4u(pg + (PSTR + 1));
                if (j == 0 && g == 0 && t == 0)   tj[0] = 0.f;   // c=0 corner
                if (j == 2 && g == 3 && t == 255) tj[3] = 0.f;   // c=4095 corner
                sA[g] += tj;
            }
        }
        int r2B = rbB + (j - 1);
        if (r2B >= 0 && r2B < LTOT) {
            int rr = ((r2B & 63) << 6) | ((r2B >> 6) & 63);
            const float* pr = Sg + (size_t)rr * PSTR + ccb;
#pragma unroll
            for (int g = 0; g < 4; ++g) {
                const float* pg = pr + 4 * g;
                f32x4 tj = ld4u(pg - (PSTR + 1)) + ld4u(pg) + ld4u(pg + (PSTR + 1));
                if (j == 0 && g == 0 && t == 0)   tj[0] = 0.f;
                if (j == 2 && g == 3 && t == 255) tj[3] = 0.f;
                sB[g] += tj;
            }
        }
    }

    float vA[16], vB[16];
#pragma unroll
    for (int g = 0; g < 4; ++g) {
        f32x4 m4 = *(const f32x4*)(mmv + c0 + 4 * g);
#pragma unroll
        for (int e = 0; e < 4; ++e) {
            vA[4 * g + e] = sA[g][e] * m4[e] * SCALE_F;
            vB[4 * g + e] = sB[g][e] * m4[e] * SCALE_F;
        }
    }
#pragma unroll
    for (int k = 0; k < 16; ++k) { asm volatile("" : "+v"(vA[k])); asm volatile("" : "+v"(vB[k])); }

    float mxA = vA[0], mxB = vB[0];
#pragma unroll
    for (int i = 1; i < 16; ++i) { mxA = fmaxf(mxA, vA[i]); mxB = fmaxf(mxB, vB[i]); }
#pragma unroll
    for (int o = 32; o; o >>= 1) { mxA = fmaxf(mxA, __shfl_xor(mxA, o)); mxB = fmaxf(mxB, __shfl_xor(mxB, o)); }
    if (lane == 0) { redmax[wid] = mxA; redmax[4 + wid] = mxB; }
    __syncthreads();
    float gmxA = fmaxf(fmaxf(redmax[0], redmax[1]), fmaxf(redmax[2], redmax[3]));
    float gmxB = fmaxf(fmaxf(redmax[4], redmax[5]), fmaxf(redmax[6], redmax[7]));

    float suA = 0.f, suB = 0.f;
#pragma unroll
    for (int i = 0; i < 16; ++i) {
        vA[i] = __expf(vA[i] - gmxA); suA += vA[i];
        vB[i] = __expf(vB[i] - gmxB); suB += vB[i];
    }
#pragma unroll
    for (int o = 32; o; o >>= 1) { suA += __shfl_xor(suA, o); suB += __shfl_xor(suB, o); }
    if (lane == 0) { redsum[wid] = suA; redsum[4 + wid] = suB; }
    __syncthreads();
    float invA = 1.f / (redsum[0] + redsum[1] + redsum[2] + redsum[3]);
    float invB = 1.f / (redsum[4] + redsum[5] + redsum[6] + redsum[7]);

    unsigned short* orowA = S16 + (size_t)qA * LTOT + c0;
    unsigned short* orowB = S16 + (size_t)qB * LTOT + c0;
    short8 hA0, hA1, hB0, hB1;
#pragma unroll
    for (int e = 0; e < 8; ++e) {
        float m0 = mmv[c0 + e], m1 = mmv[c0 + 8 + e];
        hA0[e] = (short)f2bf(vA[e]     * invA * m0);
        hA1[e] = (short)f2bf(vA[8 + e] * invA * m1);
        hB0[e] = (short)f2bf(vB[e]     * invB * m0);
        hB1[e] = (short)f2bf(vB[8 + e] * invB * m1);
    }
    *(short8*)orowA = hA0; *(short8*)(orowA + 8) = hA1;
    *(short8*)orowB = hB0; *(short8*)(orowB + 8) = hB1;
}

// ---------------- overlap-add of weighted 4x4 patches (stride 2), /4 ----------------
// C2t is TRANSPOSED and SPLIT-K: two partials [m2][q]; taps contiguous across threads (x->ox).
__global__ void output_kernel(const float* __restrict__ C2t, float* __restrict__ out) {
    const float* __restrict__ P1 = C2t + (size_t)K2 * LTOT;
    int idx = blockIdx.x * blockDim.x + threadIdx.x;   // CC*HH*WW
    int x = idx & 127;
    int y = (idx >> 7) & 127;
    int c = idx >> 14;
    int oylo = max(0, (y - 1) >> 1), oyhi = min(63, (y + 1) >> 1);
    int oxlo = max(0, (x - 1) >> 1), oxhi = min(63, (x + 1) >> 1);
    float s = 0.f;
    for (int oy = oylo; oy <= oyhi; ++oy)
        for (int ox = oxlo; ox <= oxhi; ++ox) {
            int kd = y - 2 * oy + 1;
            int ke = x - 2 * ox + 1;
            size_t off = (size_t)(c * 16 + kd * 4 + ke) * LTOT + oy * 64 + ox;
            s += C2t[off] + P1[off];
        }
    out[idx] = s * 0.25f;
}

extern "C" void kernel_launch(void* const* d_in, const int* in_sizes, int n_in,
                              void* d_out, int out_size, void* d_ws, size_t ws_size,
                              hipStream_t stream) {
    (void)in_sizes; (void)n_in; (void)out_size; (void)ws_size;
    const float* f    = (const float*)d_in[0];
    const float* b    = (const float*)d_in[1];
    const float* mask = (const float*)d_in[2];
    float* out = (float*)d_out;

    const size_t SZ_MAT  = (size_t)LTOT * LTOT * 4;        // 64 MB
    const size_t SZ_SPAD = (size_t)PSTR * 4098 * 4;        // 67.3 MB padded S (guards + col pads)
    const size_t SZ_WR   = (size_t)K2 * LTOT * 2;          // 16 MB
    const size_t SZ_SP   = (size_t)LTOT * K0S * 2;         // 3 MB
    const size_t SZ_V    = (size_t)LTOT * 4;

    auto pad = [](size_t n) { return (n + 255) & ~(size_t)255; };
    char* p = (char*)d_ws;
    auto take = [&](size_t n) -> void* { void* r = (void*)p; p += pad(n); return r; };

    // footprint: 0.25K guard + 64 + 67.3 + 16 (single W) + 4*3 + small ~= 160 MB (< proven 172)
    take(256);                                     // guard: stencil corner reads C[-1]
    float* Buf1 = (float*)take(SZ_MAT);            // Cpix -> S16 (lower 32 MB)
    float* Spad = (float*)take(SZ_SPAD);           // padded S -> C2t partials (lower 64 MB)
    unsigned short* W = (unsigned short*)take(SZ_WR);   // per-batch raw patches (im2col in loop)
    unsigned short* Bsp0 = (unsigned short*)take(SZ_SP);
    unsigned short* Fsp0 = (unsigned short*)take(SZ_SP);
    unsigned short* Bsp1 = (unsigned short*)take(SZ_SP);
    unsigned short* Fsp1 = (unsigned short*)take(SZ_SP);
    float* ssq0 = (float*)take(SZ_V);  float* ssq1 = (float*)take(SZ_V);
    float* invn0 = (float*)take(SZ_V); float* invn1 = (float*)take(SZ_V);
    float* mmv0 = (float*)take(SZ_V);  float* mmv1 = (float*)take(SZ_V);

    const float* f0 = f,  *b0 = b;
    const float* f1 = f + IMG, *b1 = b + IMG;

    float* Sg = Spad + PSTR + 4;                   // padded S row 0, col 0
    unsigned short* S16 = (unsigned short*)Buf1;   // 32 MB, after Cpix dead
    float* C2t = Spad;                             // 2 x 32 MB partials, after padded S dead

    // ---- merged prep (both batches); ssq fused into the b split passes ----
    Prep4 P{{b0, f0, b1, f1}, {Bsp0, Fsp0, Bsp1, Fsp1},
            {ssq0, nullptr, ssq1, nullptr}, {1, 0, 1, 0}};
    split_ds_kernel<<<dim3(LTOT, 1, 4), 128, 0, stream>>>(P);
    PtrN2 nm{{ssq0, ssq1}, {invn0, invn1}, {mmv0, mmv1}};
    norm_mm_kernel<<<dim3(16, 1, 2), 256, 0, stream>>>(nm, mask);

    // ---- per-batch pipeline ----
    for (int bi = 0; bi < 2; ++bi) {
        const unsigned short* Fsp = bi ? Fsp1 : Fsp0;
        const unsigned short* Bsp = bi ? Bsp1 : Bsp0;
        const float* invn = bi ? invn1 : invn0;
        const float* mmv  = bi ? mmv1 : mmv0;

        // raw 4x4 patches for this batch only (W reused across batches); px-pair threads
        PtrR2 rw{{bi ? b1 : b0, nullptr}, {W, nullptr}};
        im2col_rawt_kernel<<<dim3((size_t)K2 * LTOT / 2 / 256, 1, 1), 256, 0, stream>>>(rw);

        // Cpix[q][p] = sum_c fd[c][q]*bd[c][p]   (split-concat fp32-accurate, K=384)
        gemm_mfma<<<dim3(32, 32), 256, 0, stream>>>(Fsp, Bsp, Buf1, LTOT, LTOT, K0S);

        // patch inner products: 9-tap diagonal stencil + invn column scale -> padded S (1 q/block)
        stencil_norm_kernel<<<LTOT, 256, 0, stream>>>(Buf1, invn, Sg);

        // fused (fuse2 o fuse1) + softmax + bf16 cast  (2-q blocks; Cpix dead -> S16 in Buf1)
        fused_conv_softmax_kernel<<<2048, 256, 0, stream>>>(Sg, mmv, S16);

        // TRANSPOSED GEMM2 (ring-2 + XCD grouping, R7 body): C2t_ks[m2][q] = sum_p W[m2][p]*S16[q][p]
        gemm_k2<<<256, 512, 0, stream>>>(W, S16, C2t);

        output_kernel<<<CC * HH * WW / 256, 256, 0, stream>>>(C2t, out + (size_t)bi * IMG);
    }
}

// Round 11
// 498.659 us; speedup vs baseline: 1.1024x; 1.0047x over previous
//
#include <hip/hip_runtime.h>

#define CC 128
#define HH 128
#define WW 128
#define DH 64
#define DW 64
#define LTOT 4096          // DH*DW patches / fg positions
#define K0S 384            // 3*128 split-concat K for the pixel-pair GEMM
#define K2 2048            // CC*4*4
#define GK 4096            // GEMM2 full K
#define GKH 2048           // GEMM2 half K (split-K by 2)
#define SCALE_F 10.0f
#define IMG ((size_t)CC * HH * WW)
#define PSTR 4104          // padded S row stride (floats): 4 pad | 4096 | 4 pad; %4==0 keeps 16B align

typedef __attribute__((ext_vector_type(8))) short short8;
typedef __attribute__((ext_vector_type(4))) float f32x4;
typedef __attribute__((ext_vector_type(2))) float f32x2;

// ---- pointer-pack structs (batch-merged prep via blockIdx.z) ----
struct Prep4 { const float* src[4]; unsigned short* dst[4]; float* ssq[4]; int lo[4]; };
struct PtrN2 { const float* ssq[2]; float* invn[2]; float* mmv[2]; };
struct PtrR2 { const float* src[2]; unsigned short* dst[2]; };

// ---- bf16 helpers (RNE) ----
__device__ __forceinline__ unsigned short f2bf(float x) {
    union { float f; unsigned u; } v; v.f = x;
    unsigned r = v.u + 0x7fffu + ((v.u >> 16) & 1u);
    return (unsigned short)(r >> 16);
}
__device__ __forceinline__ float bf2f(unsigned short b) {
    union { unsigned u; float f; } v; v.u = ((unsigned)b) << 16;
    return v.f;
}

// unaligned (4B-aligned) float4 load
__device__ __forceinline__ f32x4 ld4u(const float* p) {
    f32x4 r; __builtin_memcpy(&r, p, 16); return r;
}

#define GLDS16(g, l) __builtin_amdgcn_global_load_lds( \
    (const __attribute__((address_space(1))) void*)(g), \
    (__attribute__((address_space(3))) void*)(l), 16, 0, 0)

// ---------------- downsample (::2) + fp32->bf16 split + (for b) fused ssq reduce ----------------
// b gets [hi, lo, hi], f gets [hi, hi, lo]  =>  products sum to hi*hi + lo*hi + hi*lo
__global__ __launch_bounds__(128) void split_ds_kernel(Prep4 P) {
    __shared__ float partial[2];
    int z = blockIdx.z;
    const float* __restrict__ src = P.src[z];
    unsigned short* __restrict__ dst = P.dst[z];
    int lo_in_seg1 = P.lo[z];
    int n = blockIdx.x;          // 4096 pixels
    int c = threadIdx.x;         // 128 channels
    int ny = n >> 6, nx = n & 63;
    float v = src[((size_t)c * HH + 2 * ny) * WW + 2 * nx];
    unsigned short hi = f2bf(v);
    unsigned short lo = f2bf(v - bf2f(hi));
    unsigned short* drow = dst + (size_t)n * K0S;
    drow[c]       = hi;
    drow[128 + c] = lo_in_seg1 ? lo : hi;
    drow[256 + c] = lo_in_seg1 ? hi : lo;

    float* ssq = P.ssq[z];
    if (ssq) {                   // b images only: per-pixel channel sum of squares
        float s2 = v * v;
#pragma unroll
        for (int o = 32; o; o >>= 1) s2 += __shfl_xor(s2, o);
        if ((threadIdx.x & 63) == 0) partial[threadIdx.x >> 6] = s2;
        __syncthreads();
        if (threadIdx.x == 0) ssq[n] = partial[0] + partial[1];
    }
}

// ---------------- raw 4x4 stride-2 patches of full-res b, transposed: dst[m2][p] bf16 ----------------
// R8: thread owns a px-PAIR; interior threads cover both taps with one unaligned f32x4.
__global__ __launch_bounds__(256) void im2col_rawt_kernel(PtrR2 P) {
    int z = blockIdx.z;
    const float* __restrict__ src = P.src[z];
    unsigned short* __restrict__ dst = P.dst[z];
    int idx = blockIdx.x * 256 + threadIdx.x;     // m*2048 + py*32 + u
    int u  = idx & 31;                             // px pair index: px0 = 2u
    int py = (idx >> 5) & 63;
    int m  = idx >> 11;                            // (c,kd,ke)
    int ke = m & 3, kd = (m >> 2) & 3, c = m >> 4;
    int yy = 2 * py - 1 + kd;
    int xx0 = 4 * u - 1 + ke;                      // xx for px0; px1 uses xx0+2
    unsigned short o0 = 0, o1 = 0;
    if (yy >= 0 && yy < HH) {
        const float* row = src + ((size_t)c * HH + yy) * WW;
        if (u == 0 || u == 31) {                   // edges: scalar, bounds-checked
            if (xx0 >= 0 && xx0 < WW)         o0 = f2bf(row[xx0]);
            if (xx0 + 2 >= 0 && xx0 + 2 < WW) o1 = f2bf(row[xx0 + 2]);
        } else {                                   // interior: xx0 in [3,122]
            f32x4 w = ld4u(row + xx0);
            o0 = f2bf(w[0]); o1 = f2bf(w[2]);
        }
    }
    unsigned short* dp = dst + (size_t)m * LTOT + py * 64 + 2 * u;
    dp[0] = o0; dp[1] = o1;
}

// ---------------- patch inverse norm + mask gate ----------------
__global__ void norm_mm_kernel(PtrN2 P, const float* __restrict__ mask) {
    int z = blockIdx.z;
    const float* __restrict__ ssq = P.ssq[z];
    float* __restrict__ inv_norm = P.invn[z];
    float* __restrict__ mmv = P.mmv[z];
    int p = blockIdx.x * blockDim.x + threadIdx.x;     // 4096
    int px = p & 63, py = p >> 6;
    float s = 0.f, ms = 0.f;
    for (int di = -1; di <= 1; ++di)
        for (int dj = -1; dj <= 1; ++dj) {
            int y = py + di, x = px + dj;
            if (y >= 0 && y < DH && x >= 0 && x < DW) {
                s += ssq[y * 64 + x];
                ms += mask[(size_t)(2 * y) * WW + 2 * x];
            }
        }
    float n = sqrtf(s);
    if (n < 1e-4f) n = 1e-4f;
    inv_norm[p] = 1.f / n;
    mmv[p] = (ms == 0.f) ? 1.f : 0.f;
}

// ---------------- bf16 MFMA GEMM, BK=64, hoisted running pointers, XOR swizzle ----------------
// (kept for GEMM1: M=N=4096, K=384 — short-K, 1024 blocks; operands 3MB+3MB L3-resident)
__global__ __launch_bounds__(256) void gemm_mfma(
    const unsigned short* __restrict__ Aop, const unsigned short* __restrict__ Bop,
    float* __restrict__ C, int M, int N, int K)
{
    __shared__ short As[128 * 64];
    __shared__ short Bs[128 * 64];
    int tid = threadIdx.x;
    int wave = tid >> 6, lane = tid & 63;
    int wm = (wave >> 1) * 64;
    int wn = (wave & 1) * 64;
    int bm = blockIdx.y * 128, bn = blockIdx.x * 128;

    int rowS = wave * 32;              // wave stages rows [rowS, rowS+32)
    int lrow8 = lane >> 3;             // 0..7 (row within 8-row staging group)
    int gchunk = ((lane & 7) ^ lrow8) * 8;   // swizzled global k-offset (shorts)

    f32x4 acc[4][4] = {};

    int quad = lane >> 4;              // 0..3
    int r16 = lane & 15;
    int pc0 = ((quad)     ^ (r16 & 7)) * 8;  // physical chunk of k-slab 0
    int pc1 = ((4 + quad) ^ (r16 & 7)) * 8;  // physical chunk of k-slab 1

    const unsigned short* ap0 = Aop + (size_t)(bm + rowS +  0 + lrow8) * K + gchunk;
    const unsigned short* ap1 = Aop + (size_t)(bm + rowS +  8 + lrow8) * K + gchunk;
    const unsigned short* ap2 = Aop + (size_t)(bm + rowS + 16 + lrow8) * K + gchunk;
    const unsigned short* ap3 = Aop + (size_t)(bm + rowS + 24 + lrow8) * K + gchunk;
    const unsigned short* bp0 = Bop + (size_t)(bn + rowS +  0 + lrow8) * K + gchunk;
    const unsigned short* bp1 = Bop + (size_t)(bn + rowS +  8 + lrow8) * K + gchunk;
    const unsigned short* bp2 = Bop + (size_t)(bn + rowS + 16 + lrow8) * K + gchunk;
    const unsigned short* bp3 = Bop + (size_t)(bn + rowS + 24 + lrow8) * K + gchunk;
    short* lA = As + rowS * 64;        // wave-uniform LDS bases
    short* lB = Bs + rowS * 64;

    for (int k0 = 0; k0 < K; k0 += 64) {
        GLDS16(ap0, lA);            GLDS16(ap1, lA + 8 * 64);
        GLDS16(ap2, lA + 16 * 64);  GLDS16(ap3, lA + 24 * 64);
        GLDS16(bp0, lB);            GLDS16(bp1, lB + 8 * 64);
        GLDS16(bp2, lB + 16 * 64);  GLDS16(bp3, lB + 24 * 64);
        ap0 += 64; ap1 += 64; ap2 += 64; ap3 += 64;
        bp0 += 64; bp1 += 64; bp2 += 64; bp3 += 64;
        __syncthreads();

        short8 a0[4], b0[4], a1[4], b1[4];
#pragma unroll
        for (int i = 0; i < 4; ++i) {
            a0[i] = *(const short8*)&As[(wm + i * 16 + r16) * 64 + pc0];
            b0[i] = *(const short8*)&Bs[(wn + i * 16 + r16) * 64 + pc0];
            a1[i] = *(const short8*)&As[(wm + i * 16 + r16) * 64 + pc1];
            b1[i] = *(const short8*)&Bs[(wn + i * 16 + r16) * 64 + pc1];
        }
#pragma unroll
        for (int i = 0; i < 4; ++i)
#pragma unroll
            for (int j = 0; j < 4; ++j) {
                acc[i][j] = __builtin_amdgcn_mfma_f32_16x16x32_bf16(a0[i], b0[j], acc[i][j], 0, 0, 0);
                acc[i][j] = __builtin_amdgcn_mfma_f32_16x16x32_bf16(a1[i], b1[j], acc[i][j], 0, 0, 0);
            }
        __syncthreads();
    }

    int col = lane & 15, rq = (lane >> 4) * 4;
#pragma unroll
    for (int i = 0; i < 4; ++i) {
#pragma unroll
        for (int r = 0; r < 4; ++r) {
            int m = bm + wm + i * 16 + rq + r;
#pragma unroll
            for (int j = 0; j < 4; ++j)
                C[(size_t)m * N + bn + wn + j * 16 + col] = acc[i][j][r];
        }
    }
}

// ---------------- GEMM2: 256x256, split-K/2, ring-2 counted vmcnt + XCD panel swizzle (R7 body) ----------------
// Proven best (63.5-64 µs, FETCH 49 MB). Closed after R4/R6/R8 schedule nulls.
__global__ __launch_bounds__(512, 2) void gemm_k2(
    const unsigned short* __restrict__ Aop, const unsigned short* __restrict__ Bop,
    float* __restrict__ Cpart)
{
    constexpr int NT = 32;                    // GKH / 64
    constexpr int BUFS = 512 * 64;            // shorts per ring slot (64 KB)
    __shared__ short lds[2 * BUFS];           // 128 KB
    int flat = blockIdx.x;
    int xcd  = flat & 7;
    int slot = (flat >> 3) & 3;
    int bmId = flat >> 5;                     // 0..7
    int P    = slot * 8 + xcd;                // 0..31
    int bnId = P >> 1;                        // 0..15
    int ks   = P & 1;                         // K half
    int bm = bmId * 256, bn = bnId * 256;

    int tid = threadIdx.x;
    int wave = tid >> 6, lane = tid & 63;
    int wm = (wave >> 2) * 128;               // 0,128
    int wn = (wave & 3) * 64;                 // 0,64,128,192
    int lrow8 = lane >> 3;
    int gchunk = ((lane & 7) ^ lrow8) * 8;    // pre-swizzled global k-offset (shorts)
    int r16 = lane & 15, quad = lane >> 4;
    int pc0 = ((quad)     ^ (r16 & 7)) * 8;
    int pc1 = ((4 + quad) ^ (r16 & 7)) * 8;

    const size_t ko = (size_t)ks * GKH + gchunk;
    const unsigned short* ap0 = Aop + (size_t)(bm + wave * 32 +  0 + lrow8) * GK + ko;
    const unsigned short* ap1 = Aop + (size_t)(bm + wave * 32 +  8 + lrow8) * GK + ko;
    const unsigned short* ap2 = Aop + (size_t)(bm + wave * 32 + 16 + lrow8) * GK + ko;
    const unsigned short* ap3 = Aop + (size_t)(bm + wave * 32 + 24 + lrow8) * GK + ko;
    const unsigned short* bp0 = Bop + (size_t)(bn + wave * 32 +  0 + lrow8) * GK + ko;
    const unsigned short* bp1 = Bop + (size_t)(bn + wave * 32 +  8 + lrow8) * GK + ko;
    const unsigned short* bp2 = Bop + (size_t)(bn + wave * 32 + 16 + lrow8) * GK + ko;
    const unsigned short* bp3 = Bop + (size_t)(bn + wave * 32 + 24 + lrow8) * GK + ko;

    f32x4 acc[8][4] = {};

#define STAGE2(s) do { \
    short* la = lds + (s) * BUFS + (wave * 32) * 64; \
    short* lb = lds + (s) * BUFS + 256 * 64 + (wave * 32) * 64; \
    GLDS16(ap0, la);            GLDS16(ap1, la + 8 * 64); \
    GLDS16(ap2, la + 16 * 64);  GLDS16(ap3, la + 24 * 64); \
    GLDS16(bp0, lb);            GLDS16(bp1, lb + 8 * 64); \
    GLDS16(bp2, lb + 16 * 64);  GLDS16(bp3, lb + 24 * 64); \
    ap0 += 64; ap1 += 64; ap2 += 64; ap3 += 64; \
    bp0 += 64; bp1 += 64; bp2 += 64; bp3 += 64; } while (0)

    STAGE2(0); STAGE2(1);
    asm volatile("s_waitcnt vmcnt(8)" ::: "memory");
    __builtin_amdgcn_s_barrier();
    asm volatile("" ::: "memory");

    int buf = 0;
#pragma unroll 1
    for (int T = 0; T < NT; ++T) {
        const short* Ab = lds + buf * BUFS;
        const short* Bb = Ab + 256 * 64;
        short8 a0[8], a1[8], b0[4], b1[4];
#pragma unroll
        for (int j = 0; j < 4; ++j) {
            b0[j] = *(const short8*)&Bb[(wn + j * 16 + r16) * 64 + pc0];
            b1[j] = *(const short8*)&Bb[(wn + j * 16 + r16) * 64 + pc1];
        }
        a0[0] = *(const short8*)&Ab[(wm + r16) * 64 + pc0];
        a1[0] = *(const short8*)&Ab[(wm + r16) * 64 + pc1];
#pragma unroll
        for (int i = 0; i < 8; ++i) {
            if (i < 7) {
                a0[i + 1] = *(const short8*)&Ab[(wm + (i + 1) * 16 + r16) * 64 + pc0];
                a1[i + 1] = *(const short8*)&Ab[(wm + (i + 1) * 16 + r16) * 64 + pc1];
                asm volatile("s_waitcnt lgkmcnt(2)" ::: "memory");   // all but newest a-pair done
            } else {
                asm volatile("s_waitcnt lgkmcnt(0)" ::: "memory");
            }
            __builtin_amdgcn_sched_barrier(0);                       // rule 18: pin MFMA below wait
            __builtin_amdgcn_s_setprio(1);
#pragma unroll
            for (int j = 0; j < 4; ++j) {
                acc[i][j] = __builtin_amdgcn_mfma_f32_16x16x32_bf16(a0[i], b0[j], acc[i][j], 0, 0, 0);
                acc[i][j] = __builtin_amdgcn_mfma_f32_16x16x32_bf16(a1[i], b1[j], acc[i][j], 0, 0, 0);
            }
            __builtin_amdgcn_s_setprio(0);
        }
        asm volatile("s_waitcnt vmcnt(0)" ::: "memory");
        __builtin_amdgcn_s_barrier();
        asm volatile("" ::: "memory");
        if (T + 2 < NT) STAGE2(buf);
        buf ^= 1;
    }
#undef STAGE2

    float* Cout = Cpart + (size_t)ks * K2 * LTOT;
    int col = lane & 15, rq = (lane >> 4) * 4;
#pragma unroll
    for (int i = 0; i < 8; ++i) {
#pragma unroll
        for (int r = 0; r < 4; ++r) {
            int m = bm + wm + i * 16 + rq + r;
#pragma unroll
            for (int j = 0; j < 4; ++j)
                Cout[(size_t)m * LTOT + bn + wn + j * 16 + col] = acc[i][j][r];
        }
    }
}

// ---------------- 9-tap patch stencil, 2-q PAIRED (q, q+1 same qy): R9-fused's proven dosage ----------------
// R11: fused-2q (12 streams) won in R9 while stencil-4q (36 streams) thrashed. Pair
// (q, q+1): per (du,dv) tap, row B = row A + LTOT (same column window), so streams/block
// stay ~12, per-thread MLP doubles, L2 row-visits x0.67. Per-q tap order and masks
// unchanged -> bit-identical. qx even (<=62): A-row invalid only (qx=0,dv=-1); B-row
// invalid only (qx=62,dv=+1).
__global__ __launch_bounds__(256) void stencil_norm_kernel(
    const float* __restrict__ C, const float* __restrict__ invn,
    float* __restrict__ Sg)
{
    int blk = blockIdx.x;                    // 2048
    int h = ((blk & 7) << 8) | (blk >> 3);   // XCD swizzle: 256 contiguous pairs per XCD
    int q = h << 1;                          // even q; this block does q and q+1
    int t = threadIdx.x;
    int qy = q >> 6, qx = q & 63;            // qx even
    int chunk = t >> 2;                      // py (uniform over the 16 cols)
    int lanebase = (t & 3) << 4;             // px of first col
    int p0 = t << 4;

    f32x4 accA[4], accB[4];
#pragma unroll
    for (int g = 0; g < 4; ++g) {
        accA[g][0] = accA[g][1] = accA[g][2] = accA[g][3] = 0.f;
        accB[g][0] = accB[g][1] = accB[g][2] = accB[g][3] = 0.f;
    }

#pragma unroll
    for (int du = -1; du <= 1; ++du) {
        if (qy + du < 0 || qy + du > 63) continue;
        if (chunk + du < 0 || chunk + du > 63) continue;   // py+du (uniform)
#pragma unroll
        for (int dv = -1; dv <= 1; ++dv) {
            const float* rp = C + (size_t)(q + 64 * du + dv) * LTOT + 64 * du + dv + p0;
            if (qx + dv >= 0) {                            // A valid (upper bound always ok)
#pragma unroll
                for (int g = 0; g < 4; ++g) {
                    f32x4 lv = ld4u(rp + 4 * g);
                    if (dv == -1 && g == 0 && lanebase == 0)  lv[0] = 0.f;  // px+dv = -1
                    if (dv ==  1 && g == 3 && lanebase == 48) lv[3] = 0.f;  // px+dv = 64
                    accA[g] += lv;
                }
            }
            if (qx + 1 + dv <= 63) {                       // B valid (lower bound always ok)
                const float* rpB = rp + LTOT;
#pragma unroll
                for (int g = 0; g < 4; ++g) {
                    f32x4 lv = ld4u(rpB + 4 * g);
                    if (dv == -1 && g == 0 && lanebase == 0)  lv[0] = 0.f;
                    if (dv ==  1 && g == 3 && lanebase == 48) lv[3] = 0.f;
                    accB[g] += lv;
                }
            }
        }
    }
    {
        float* orow = Sg + (size_t)q * PSTR;
#pragma unroll
        for (int g = 0; g < 4; ++g) {
            f32x4 iv = *(const f32x4*)(invn + p0 + 4 * g);
            *(f32x4*)(orow + p0 + 4 * g) = accA[g] * iv;
        }
        if (t == 0) { orow[-4] = orow[-3] = orow[-2] = orow[-1] = 0.f; }
        else if (t == 1) { orow[4096] = orow[4097] = orow[4098] = orow[4099] = 0.f; }
    }
    {
        float* orow = Sg + (size_t)(q + 1) * PSTR;
#pragma unroll
        for (int g = 0; g < 4; ++g) {
            f32x4 iv = *(const f32x4*)(invn + p0 + 4 * g);
            *(f32x4*)(orow + p0 + 4 * g) = accB[g] * iv;
        }
        if (t == 2) { orow[-4] = orow[-3] = orow[-2] = orow[-1] = 0.f; }
        else if (t == 3) { orow[4096] = orow[4097] = orow[4098] = orow[4099] = 0.f; }
    }
    // zero guard rows -1 and 4096 (full padded rows)
    if (q == 0) {
        float* gr = Sg - 4 - PSTR;
        for (int k = t; k < PSTR; k += 256) gr[k] = 0.f;
    }
    if (q == 4094) {
        float* gr = Sg - 4 + (size_t)4096 * PSTR;
        for (int k = t; k < PSTR; k += 256) gr[k] = 0.f;
    }
}

// ---------------- fused (fuse2 o fuse1) stencil + row softmax + bf16, 2-q blocked (R9 win) ----------------
__global__ __launch_bounds__(256) void fused_conv_softmax_kernel(
    const float* __restrict__ Sg, const float* __restrict__ mmv,
    unsigned short* __restrict__ S16)
{
    __shared__ float redmax[8];
    __shared__ float redsum[8];
    int blk = blockIdx.x;                       // 2048
    int h = ((blk & 7) << 8) | (blk >> 3);      // XCD swizzle on pair index
    int qx = h & 63, qy2 = h >> 6;              // qy2 0..31
    int qA = (2 * qy2) * 64 + qx;               // sub0 (qy even)
    int qB = qA + 64;                           // sub1 (qy odd)
    int t = threadIdx.x;
    int lane = t & 63, wid = t >> 6;
    int chunk = t >> 2;
    int lanebase = (t & 3) << 4;
    int c0 = t << 4;

    int rbA = ((qA & 63) << 6) | (qA >> 6);     // swap(qA)
    int rbB = rbA + 1;                          // swap(qB) (qy odd, no field overflow)

    f32x4 sA[4], sB[4];
#pragma unroll
    for (int g = 0; g < 4; ++g) {
        sA[g][0] = sA[g][1] = sA[g][2] = sA[g][3] = 0.f;
        sB[g][0] = sB[g][1] = sB[g][2] = sB[g][3] = 0.f;
    }

#pragma unroll
    for (int j = 0; j < 3; ++j) {               // d2 = j-1
        int cj = chunk + (j - 1);
        int ccb;
        if (cj < 0)       ccb = 4031 + lanebase;
        else if (cj > 63) ccb = lanebase + 1;
        else              ccb = (cj << 6) + lanebase;

        int r2A = rbA + (j - 1);
        if (r2A >= 0 && r2A < LTOT) {
            int rr = ((r2A & 63) << 6) | ((r2A >> 6) & 63);
            const float* pr = Sg + (size_t)rr * PSTR + ccb;
#pragma unroll
            for (int g = 0; g < 4; ++g) {
                const float* pg = pr + 4 * g;
                f32x4 tj = ld4u(pg - (PSTR + 1)) + ld4u(pg) + ld4u(pg + (PSTR + 1));
                if (j == 0 && g == 0 && t == 0)   tj[0] = 0.f;   // c=0 corner
                if (j == 2 && g == 3 && t == 255) tj[3] = 0.f;   // c=4095 corner
                sA[g] += tj;
            }
        }
        int r2B = rbB + (j - 1);
        if (r2B >= 0 && r2B < LTOT) {
            int rr = ((r2B & 63) << 6) | ((r2B >> 6) & 63);
            const float* pr = Sg + (size_t)rr * PSTR + ccb;
#pragma unroll
            for (int g = 0; g < 4; ++g) {
                const float* pg = pr + 4 * g;
                f32x4 tj = ld4u(pg - (PSTR + 1)) + ld4u(pg) + ld4u(pg + (PSTR + 1));
                if (j == 0 && g == 0 && t == 0)   tj[0] = 0.f;
                if (j == 2 && g == 3 && t == 255) tj[3] = 0.f;
                sB[g] += tj;
            }
        }
    }

    float vA[16], vB[16];
#pragma unroll
    for (int g = 0; g < 4; ++g) {
        f32x4 m4 = *(const f32x4*)(mmv + c0 + 4 * g);
#pragma unroll
        for (int e = 0; e < 4; ++e) {
            vA[4 * g + e] = sA[g][e] * m4[e] * SCALE_F;
            vB[4 * g + e] = sB[g][e] * m4[e] * SCALE_F;
        }
    }
#pragma unroll
    for (int k = 0; k < 16; ++k) { asm volatile("" : "+v"(vA[k])); asm volatile("" : "+v"(vB[k])); }

    float mxA = vA[0], mxB = vB[0];
#pragma unroll
    for (int i = 1; i < 16; ++i) { mxA = fmaxf(mxA, vA[i]); mxB = fmaxf(mxB, vB[i]); }
#pragma unroll
    for (int o = 32; o; o >>= 1) { mxA = fmaxf(mxA, __shfl_xor(mxA, o)); mxB = fmaxf(mxB, __shfl_xor(mxB, o)); }
    if (lane == 0) { redmax[wid] = mxA; redmax[4 + wid] = mxB; }
    __syncthreads();
    float gmxA = fmaxf(fmaxf(redmax[0], redmax[1]), fmaxf(redmax[2], redmax[3]));
    float gmxB = fmaxf(fmaxf(redmax[4], redmax[5]), fmaxf(redmax[6], redmax[7]));

    float suA = 0.f, suB = 0.f;
#pragma unroll
    for (int i = 0; i < 16; ++i) {
        vA[i] = __expf(vA[i] - gmxA); suA += vA[i];
        vB[i] = __expf(vB[i] - gmxB); suB += vB[i];
    }
#pragma unroll
    for (int o = 32; o; o >>= 1) { suA += __shfl_xor(suA, o); suB += __shfl_xor(suB, o); }
    if (lane == 0) { redsum[wid] = suA; redsum[4 + wid] = suB; }
    __syncthreads();
    float invA = 1.f / (redsum[0] + redsum[1] + redsum[2] + redsum[3]);
    float invB = 1.f / (redsum[4] + redsum[5] + redsum[6] + redsum[7]);

    unsigned short* orowA = S16 + (size_t)qA * LTOT + c0;
    unsigned short* orowB = S16 + (size_t)qB * LTOT + c0;
    short8 hA0, hA1, hB0, hB1;
#pragma unroll
    for (int e = 0; e < 8; ++e) {
        float m0 = mmv[c0 + e], m1 = mmv[c0 + 8 + e];
        hA0[e] = (short)f2bf(vA[e]     * invA * m0);
        hA1[e] = (short)f2bf(vA[8 + e] * invA * m1);
        hB0[e] = (short)f2bf(vB[e]     * invB * m0);
        hB1[e] = (short)f2bf(vB[8 + e] * invB * m1);
    }
    *(short8*)orowA = hA0; *(short8*)(orowA + 8) = hA1;
    *(short8*)orowB = hB0; *(short8*)(orowB + 8) = hB1;
}

// ---------------- overlap-add of weighted 4x4 patches (stride 2), /4 — 2x2 OUTPUT TILE ----------------
// R11: thread owns (y in {2a,2a+1}) x (x in {2b,2b+1}). Consecutive lanes -> consecutive b
// -> every plane-read fully coalesced with ALL lanes active (old version: parity-split,
// half the lanes idle per plane). Per-output (oy,ox) order unchanged -> bit-identical.
// float2 stores. C2t is TRANSPOSED and SPLIT-K: two partials [m2][q].
__global__ void output_kernel(const float* __restrict__ C2t, float* __restrict__ out) {
    const float* __restrict__ P1 = C2t + (size_t)K2 * LTOT;
    int idx = blockIdx.x * blockDim.x + threadIdx.x;   // c*4096 + a*64 + b
    int b = idx & 63;
    int a = (idx >> 6) & 63;
    int c = idx >> 12;
#pragma unroll
    for (int dy = 0; dy < 2; ++dy) {
        int y = 2 * a + dy;
        float r[2];
#pragma unroll
        for (int dx = 0; dx < 2; ++dx) {
            int x = 2 * b + dx;
            int oylo = max(0, (y - 1) >> 1), oyhi = min(63, (y + 1) >> 1);
            int oxlo = max(0, (x - 1) >> 1), oxhi = min(63, (x + 1) >> 1);
            float s = 0.f;
            for (int oy = oylo; oy <= oyhi; ++oy)
                for (int ox = oxlo; ox <= oxhi; ++ox) {
                    int kd = y - 2 * oy + 1;
                    int ke = x - 2 * ox + 1;
                    size_t off = (size_t)(c * 16 + kd * 4 + ke) * LTOT + oy * 64 + ox;
                    s += C2t[off] + P1[off];
                }
            r[dx] = s * 0.25f;
        }
        f32x2 w; w[0] = r[0]; w[1] = r[1];
        *(f32x2*)(out + ((size_t)c * HH + y) * WW + 2 * b) = w;
    }
}

extern "C" void kernel_launch(void* const* d_in, const int* in_sizes, int n_in,
                              void* d_out, int out_size, void* d_ws, size_t ws_size,
                              hipStream_t stream) {
    (void)in_sizes; (void)n_in; (void)out_size; (void)ws_size;
    const float* f    = (const float*)d_in[0];
    const float* b    = (const float*)d_in[1];
    const float* mask = (const float*)d_in[2];
    float* out = (float*)d_out;

    const size_t SZ_MAT  = (size_t)LTOT * LTOT * 4;        // 64 MB
    const size_t SZ_SPAD = (size_t)PSTR * 4098 * 4;        // 67.3 MB padded S (guards + col pads)
    const size_t SZ_WR   = (size_t)K2 * LTOT * 2;          // 16 MB
    const size_t SZ_SP   = (size_t)LTOT * K0S * 2;         // 3 MB
    const size_t SZ_V    = (size_t)LTOT * 4;

    auto pad = [](size_t n) { return (n + 255) & ~(size_t)255; };
    char* p = (char*)d_ws;
    auto take = [&](size_t n) -> void* { void* r = (void*)p; p += pad(n); return r; };

    // footprint: 0.25K guard + 64 + 67.3 + 16 (single W) + 4*3 + small ~= 160 MB (< proven 172)
    take(256);                                     // guard: stencil corner reads C[-1]
    float* Buf1 = (float*)take(SZ_MAT);            // Cpix -> S16 (lower 32 MB)
    float* Spad = (float*)take(SZ_SPAD);           // padded S -> C2t partials (lower 64 MB)
    unsigned short* W = (unsigned short*)take(SZ_WR);   // per-batch raw patches (im2col in loop)
    unsigned short* Bsp0 = (unsigned short*)take(SZ_SP);
    unsigned short* Fsp0 = (unsigned short*)take(SZ_SP);
    unsigned short* Bsp1 = (unsigned short*)take(SZ_SP);
    unsigned short* Fsp1 = (unsigned short*)take(SZ_SP);
    float* ssq0 = (float*)take(SZ_V);  float* ssq1 = (float*)take(SZ_V);
    float* invn0 = (float*)take(SZ_V); float* invn1 = (float*)take(SZ_V);
    float* mmv0 = (float*)take(SZ_V);  float* mmv1 = (float*)take(SZ_V);

    const float* f0 = f,  *b0 = b;
    const float* f1 = f + IMG, *b1 = b + IMG;

    float* Sg = Spad + PSTR + 4;                   // padded S row 0, col 0
    unsigned short* S16 = (unsigned short*)Buf1;   // 32 MB, after Cpix dead
    float* C2t = Spad;                             // 2 x 32 MB partials, after padded S dead

    // ---- merged prep (both batches); ssq fused into the b split passes ----
    Prep4 P{{b0, f0, b1, f1}, {Bsp0, Fsp0, Bsp1, Fsp1},
            {ssq0, nullptr, ssq1, nullptr}, {1, 0, 1, 0}};
    split_ds_kernel<<<dim3(LTOT, 1, 4), 128, 0, stream>>>(P);
    PtrN2 nm{{ssq0, ssq1}, {invn0, invn1}, {mmv0, mmv1}};
    norm_mm_kernel<<<dim3(16, 1, 2), 256, 0, stream>>>(nm, mask);

    // ---- per-batch pipeline ----
    for (int bi = 0; bi < 2; ++bi) {
        const unsigned short* Fsp = bi ? Fsp1 : Fsp0;
        const unsigned short* Bsp = bi ? Bsp1 : Bsp0;
        const float* invn = bi ? invn1 : invn0;
        const float* mmv  = bi ? mmv1 : mmv0;

        // raw 4x4 patches for this batch only (W reused across batches); px-pair threads
        PtrR2 rw{{bi ? b1 : b0, nullptr}, {W, nullptr}};
        im2col_rawt_kernel<<<dim3((size_t)K2 * LTOT / 2 / 256, 1, 1), 256, 0, stream>>>(rw);

        // Cpix[q][p] = sum_c fd[c][q]*bd[c][p]   (split-concat fp32-accurate, K=384)
        gemm_mfma<<<dim3(32, 32), 256, 0, stream>>>(Fsp, Bsp, Buf1, LTOT, LTOT, K0S);

        // patch inner products: 9-tap diagonal stencil + invn column scale -> padded S (2-q pairs)
        stencil_norm_kernel<<<2048, 256, 0, stream>>>(Buf1, invn, Sg);

        // fused (fuse2 o fuse1) + softmax + bf16 cast  (2-q blocks; Cpix dead -> S16 in Buf1)
        fused_conv_softmax_kernel<<<2048, 256, 0, stream>>>(Sg, mmv, S16);

        // TRANSPOSED GEMM2 (ring-2 + XCD grouping, R7 body): C2t_ks[m2][q] = sum_p W[m2][p]*S16[q][p]
        gemm_k2<<<256, 512, 0, stream>>>(W, S16, C2t);

        // overlap-add, 2x2 output tile per thread
        output_kernel<<<CC * HH * WW / 4 / 256, 256, 0, stream>>>(C2t, out + (size_t)bi * IMG);
    }
}

// Round 12
// 494.701 us; speedup vs baseline: 1.1112x; 1.0080x over previous
//
#include <hip/hip_runtime.h>

#define CC 128
#define HH 128
#define WW 128
#define DH 64
#define DW 64
#define LTOT 4096          // DH*DW patches / fg positions
#define K0S 384            // 3*128 split-concat K for the pixel-pair GEMM
#define K2 2048            // CC*4*4
#define GK 4096            // GEMM2 full K
#define GKH 2048           // GEMM2 half K (split-K by 2)
#define SCALE_F 10.0f
#define IMG ((size_t)CC * HH * WW)
#define PSTR 4104          // padded S row stride (floats): 4 pad | 4096 | 4 pad; %4==0 keeps 16B align

typedef __attribute__((ext_vector_type(8))) short short8;
typedef __attribute__((ext_vector_type(4))) float f32x4;
typedef __attribute__((ext_vector_type(2))) float f32x2;

// ---- pointer-pack structs (batch-merged prep via blockIdx.z) ----
struct Prep4 { const float* src[4]; unsigned short* dst[4]; float* ssq[4]; int lo[4]; };
struct PtrN2 { const float* ssq[2]; float* invn[2]; float* mmv[2]; };
struct PtrR2 { const float* src[2]; unsigned short* dst[2]; };

// ---- bf16 helpers (RNE) ----
__device__ __forceinline__ unsigned short f2bf(float x) {
    union { float f; unsigned u; } v; v.f = x;
    unsigned r = v.u + 0x7fffu + ((v.u >> 16) & 1u);
    return (unsigned short)(r >> 16);
}
__device__ __forceinline__ float bf2f(unsigned short b) {
    union { unsigned u; float f; } v; v.u = ((unsigned)b) << 16;
    return v.f;
}

// unaligned (4B-aligned) float4 load
__device__ __forceinline__ f32x4 ld4u(const float* p) {
    f32x4 r; __builtin_memcpy(&r, p, 16); return r;
}

#define GLDS16(g, l) __builtin_amdgcn_global_load_lds( \
    (const __attribute__((address_space(1))) void*)(g), \
    (__attribute__((address_space(3))) void*)(l), 16, 0, 0)

// ---------------- downsample (::2) + fp32->bf16 split + (for b) fused ssq reduce ----------------
// b gets [hi, lo, hi], f gets [hi, hi, lo]  =>  products sum to hi*hi + lo*hi + hi*lo
__global__ __launch_bounds__(128) void split_ds_kernel(Prep4 P) {
    __shared__ float partial[2];
    int z = blockIdx.z;
    const float* __restrict__ src = P.src[z];
    unsigned short* __restrict__ dst = P.dst[z];
    int lo_in_seg1 = P.lo[z];
    int n = blockIdx.x;          // 4096 pixels
    int c = threadIdx.x;         // 128 channels
    int ny = n >> 6, nx = n & 63;
    float v = src[((size_t)c * HH + 2 * ny) * WW + 2 * nx];
    unsigned short hi = f2bf(v);
    unsigned short lo = f2bf(v - bf2f(hi));
    unsigned short* drow = dst + (size_t)n * K0S;
    drow[c]       = hi;
    drow[128 + c] = lo_in_seg1 ? lo : hi;
    drow[256 + c] = lo_in_seg1 ? hi : lo;

    float* ssq = P.ssq[z];
    if (ssq) {                   // b images only: per-pixel channel sum of squares
        float s2 = v * v;
#pragma unroll
        for (int o = 32; o; o >>= 1) s2 += __shfl_xor(s2, o);
        if ((threadIdx.x & 63) == 0) partial[threadIdx.x >> 6] = s2;
        __syncthreads();
        if (threadIdx.x == 0) ssq[n] = partial[0] + partial[1];
    }
}

// ---------------- raw 4x4 stride-2 patches of full-res b, transposed: dst[m2][p] bf16 ----------------
// R8: thread owns a px-PAIR; interior threads cover both taps with one unaligned f32x4.
__global__ __launch_bounds__(256) void im2col_rawt_kernel(PtrR2 P) {
    int z = blockIdx.z;
    const float* __restrict__ src = P.src[z];
    unsigned short* __restrict__ dst = P.dst[z];
    int idx = blockIdx.x * 256 + threadIdx.x;     // m*2048 + py*32 + u
    int u  = idx & 31;                             // px pair index: px0 = 2u
    int py = (idx >> 5) & 63;
    int m  = idx >> 11;                            // (c,kd,ke)
    int ke = m & 3, kd = (m >> 2) & 3, c = m >> 4;
    int yy = 2 * py - 1 + kd;
    int xx0 = 4 * u - 1 + ke;                      // xx for px0; px1 uses xx0+2
    unsigned short o0 = 0, o1 = 0;
    if (yy >= 0 && yy < HH) {
        const float* row = src + ((size_t)c * HH + yy) * WW;
        if (u == 0 || u == 31) {                   // edges: scalar, bounds-checked
            if (xx0 >= 0 && xx0 < WW)         o0 = f2bf(row[xx0]);
            if (xx0 + 2 >= 0 && xx0 + 2 < WW) o1 = f2bf(row[xx0 + 2]);
        } else {                                   // interior: xx0 in [3,122]
            f32x4 w = ld4u(row + xx0);
            o0 = f2bf(w[0]); o1 = f2bf(w[2]);
        }
    }
    unsigned short* dp = dst + (size_t)m * LTOT + py * 64 + 2 * u;
    dp[0] = o0; dp[1] = o1;
}

// ---------------- patch inverse norm + mask gate ----------------
__global__ void norm_mm_kernel(PtrN2 P, const float* __restrict__ mask) {
    int z = blockIdx.z;
    const float* __restrict__ ssq = P.ssq[z];
    float* __restrict__ inv_norm = P.invn[z];
    float* __restrict__ mmv = P.mmv[z];
    int p = blockIdx.x * blockDim.x + threadIdx.x;     // 4096
    int px = p & 63, py = p >> 6;
    float s = 0.f, ms = 0.f;
    for (int di = -1; di <= 1; ++di)
        for (int dj = -1; dj <= 1; ++dj) {
            int y = py + di, x = px + dj;
            if (y >= 0 && y < DH && x >= 0 && x < DW) {
                s += ssq[y * 64 + x];
                ms += mask[(size_t)(2 * y) * WW + 2 * x];
            }
        }
    float n = sqrtf(s);
    if (n < 1e-4f) n = 1e-4f;
    inv_norm[p] = 1.f / n;
    mmv[p] = (ms == 0.f) ? 1.f : 0.f;
}

// ---------------- bf16 MFMA GEMM, BK=64, hoisted running pointers, XOR swizzle ----------------
// (kept for GEMM1: M=N=4096, K=384 — short-K, 1024 blocks; operands 3MB+3MB L3-resident)
__global__ __launch_bounds__(256) void gemm_mfma(
    const unsigned short* __restrict__ Aop, const unsigned short* __restrict__ Bop,
    float* __restrict__ C, int M, int N, int K)
{
    __shared__ short As[128 * 64];
    __shared__ short Bs[128 * 64];
    int tid = threadIdx.x;
    int wave = tid >> 6, lane = tid & 63;
    int wm = (wave >> 1) * 64;
    int wn = (wave & 1) * 64;
    int bm = blockIdx.y * 128, bn = blockIdx.x * 128;

    int rowS = wave * 32;              // wave stages rows [rowS, rowS+32)
    int lrow8 = lane >> 3;             // 0..7 (row within 8-row staging group)
    int gchunk = ((lane & 7) ^ lrow8) * 8;   // swizzled global k-offset (shorts)

    f32x4 acc[4][4] = {};

    int quad = lane >> 4;              // 0..3
    int r16 = lane & 15;
    int pc0 = ((quad)     ^ (r16 & 7)) * 8;  // physical chunk of k-slab 0
    int pc1 = ((4 + quad) ^ (r16 & 7)) * 8;  // physical chunk of k-slab 1

    const unsigned short* ap0 = Aop + (size_t)(bm + rowS +  0 + lrow8) * K + gchunk;
    const unsigned short* ap1 = Aop + (size_t)(bm + rowS +  8 + lrow8) * K + gchunk;
    const unsigned short* ap2 = Aop + (size_t)(bm + rowS + 16 + lrow8) * K + gchunk;
    const unsigned short* ap3 = Aop + (size_t)(bm + rowS + 24 + lrow8) * K + gchunk;
    const unsigned short* bp0 = Bop + (size_t)(bn + rowS +  0 + lrow8) * K + gchunk;
    const unsigned short* bp1 = Bop + (size_t)(bn + rowS +  8 + lrow8) * K + gchunk;
    const unsigned short* bp2 = Bop + (size_t)(bn + rowS + 16 + lrow8) * K + gchunk;
    const unsigned short* bp3 = Bop + (size_t)(bn + rowS + 24 + lrow8) * K + gchunk;
    short* lA = As + rowS * 64;        // wave-uniform LDS bases
    short* lB = Bs + rowS * 64;

    for (int k0 = 0; k0 < K; k0 += 64) {
        GLDS16(ap0, lA);            GLDS16(ap1, lA + 8 * 64);
        GLDS16(ap2, lA + 16 * 64);  GLDS16(ap3, lA + 24 * 64);
        GLDS16(bp0, lB);            GLDS16(bp1, lB + 8 * 64);
        GLDS16(bp2, lB + 16 * 64);  GLDS16(bp3, lB + 24 * 64);
        ap0 += 64; ap1 += 64; ap2 += 64; ap3 += 64;
        bp0 += 64; bp1 += 64; bp2 += 64; bp3 += 64;
        __syncthreads();

        short8 a0[4], b0[4], a1[4], b1[4];
#pragma unroll
        for (int i = 0; i < 4; ++i) {
            a0[i] = *(const short8*)&As[(wm + i * 16 + r16) * 64 + pc0];
            b0[i] = *(const short8*)&Bs[(wn + i * 16 + r16) * 64 + pc0];
            a1[i] = *(const short8*)&As[(wm + i * 16 + r16) * 64 + pc1];
            b1[i] = *(const short8*)&Bs[(wn + i * 16 + r16) * 64 + pc1];
        }
#pragma unroll
        for (int i = 0; i < 4; ++i)
#pragma unroll
            for (int j = 0; j < 4; ++j) {
                acc[i][j] = __builtin_amdgcn_mfma_f32_16x16x32_bf16(a0[i], b0[j], acc[i][j], 0, 0, 0);
                acc[i][j] = __builtin_amdgcn_mfma_f32_16x16x32_bf16(a1[i], b1[j], acc[i][j], 0, 0, 0);
            }
        __syncthreads();
    }

    int col = lane & 15, rq = (lane >> 4) * 4;
#pragma unroll
    for (int i = 0; i < 4; ++i) {
#pragma unroll
        for (int r = 0; r < 4; ++r) {
            int m = bm + wm + i * 16 + rq + r;
#pragma unroll
            for (int j = 0; j < 4; ++j)
                C[(size_t)m * N + bn + wn + j * 16 + col] = acc[i][j][r];
        }
    }
}

// ---------------- GEMM2: 128x128 tile, BK=64, split-K/2, ring-2 counted vmcnt, 2 BLOCKS/CU ----------------
// R12: every prior gemm_k2 ran 1 block/CU (>=128 KB LDS) -> barrier-locked waves serialize
// the LDS-read phase (~37 µs/CU floor) and MFMA phase (~33 µs/CU floor) to the observed
// ~65 µs. Untested axis: occupancy. 128x128/BK=64/4-wave/ring-2 = 64 KB LDS -> 2 resident
// blocks/CU; when one block sits in lgkmcnt/barrier the other issues MFMA (m114: co-resident
// waves on MFMA vs VALU/LDS pipes overlap fully). Body = R5's proven ring-2 counted-vmcnt
// loop + gemm_mfma's proven 2x2-wave fragment/staging/swizzle. Grid 1024 = 2/CU x 256 CU x
// 2 clean block-waves. XCD grouping: 4 consecutive bn per XCD (B-panels L2-local).
// Accumulation order per (m,q) unchanged (k ascending, slab0 then slab1) -> bit-identical.
__global__ __launch_bounds__(256, 2) void gemm_k2(
    const unsigned short* __restrict__ Aop, const unsigned short* __restrict__ Bop,
    float* __restrict__ Cpart)
{
    constexpr int NT = 32;                    // GKH / 64
    constexpr int BUFS = 256 * 64;            // shorts per ring slot (32 KB: A[128][64]+B[128][64])
    __shared__ short lds[2 * BUFS];           // 64 KB -> 2 blocks/CU
    int flat = blockIdx.x;                    // 1024
    int xcd  = flat & 7;
    int r    = flat >> 3;                     // 0..127
    int bnId = xcd * 4 + (r & 3);             // 0..31 (4 bn-panels per XCD)
    int bmId = (r >> 2) & 15;                 // 0..15
    int ks   = r >> 6;                        // 0..1
    int bm = bmId * 128, bn = bnId * 128;

    int tid = threadIdx.x;
    int wave = tid >> 6, lane = tid & 63;
    int wm = (wave >> 1) * 64;
    int wn = (wave & 1) * 64;
    int rowS = wave * 32;                     // wave stages rows [rowS, rowS+32) of A and B
    int lrow8 = lane >> 3;
    int gchunk = ((lane & 7) ^ lrow8) * 8;    // pre-swizzled global k-offset (shorts)
    int r16 = lane & 15, quad = lane >> 4;
    int pc0 = ((quad)     ^ (r16 & 7)) * 8;
    int pc1 = ((4 + quad) ^ (r16 & 7)) * 8;

    const size_t ko = (size_t)ks * GKH + gchunk;
    const unsigned short* ap0 = Aop + (size_t)(bm + rowS +  0 + lrow8) * GK + ko;
    const unsigned short* ap1 = Aop + (size_t)(bm + rowS +  8 + lrow8) * GK + ko;
    const unsigned short* ap2 = Aop + (size_t)(bm + rowS + 16 + lrow8) * GK + ko;
    const unsigned short* ap3 = Aop + (size_t)(bm + rowS + 24 + lrow8) * GK + ko;
    const unsigned short* bp0 = Bop + (size_t)(bn + rowS +  0 + lrow8) * GK + ko;
    const unsigned short* bp1 = Bop + (size_t)(bn + rowS +  8 + lrow8) * GK + ko;
    const unsigned short* bp2 = Bop + (size_t)(bn + rowS + 16 + lrow8) * GK + ko;
    const unsigned short* bp3 = Bop + (size_t)(bn + rowS + 24 + lrow8) * GK + ko;

    f32x4 acc[4][4] = {};

#define STAGE2(s) do { \
    short* la = lds + (s) * BUFS + rowS * 64; \
    short* lb = lds + (s) * BUFS + 128 * 64 + rowS * 64; \
    GLDS16(ap0, la);            GLDS16(ap1, la + 8 * 64); \
    GLDS16(ap2, la + 16 * 64);  GLDS16(ap3, la + 24 * 64); \
    GLDS16(bp0, lb);            GLDS16(bp1, lb + 8 * 64); \
    GLDS16(bp2, lb + 16 * 64);  GLDS16(bp3, lb + 24 * 64); \
    ap0 += 64; ap1 += 64; ap2 += 64; ap3 += 64; \
    bp0 += 64; bp1 += 64; bp2 += 64; bp3 += 64; } while (0)

    // prologue: tiles 0,1; require tile 0 resident (tile 1's 8 loads stay in flight)
    STAGE2(0); STAGE2(1);
    asm volatile("s_waitcnt vmcnt(8)" ::: "memory");
    __builtin_amdgcn_s_barrier();
    asm volatile("" ::: "memory");

    int buf = 0;
#pragma unroll 1
    for (int T = 0; T < NT; ++T) {
        const short* Ab = lds + buf * BUFS;
        const short* Bb = Ab + 128 * 64;
        short8 a0[4], a1[4], b0[4], b1[4];
#pragma unroll
        for (int i = 0; i < 4; ++i) {
            a0[i] = *(const short8*)&Ab[(wm + i * 16 + r16) * 64 + pc0];
            a1[i] = *(const short8*)&Ab[(wm + i * 16 + r16) * 64 + pc1];
            b0[i] = *(const short8*)&Bb[(wn + i * 16 + r16) * 64 + pc0];
            b1[i] = *(const short8*)&Bb[(wn + i * 16 + r16) * 64 + pc1];
        }
        asm volatile("s_waitcnt lgkmcnt(0)" ::: "memory");
        __builtin_amdgcn_sched_barrier(0);                 // rule 18: pin MFMA below wait
        __builtin_amdgcn_s_setprio(1);
#pragma unroll
        for (int i = 0; i < 4; ++i)
#pragma unroll
            for (int j = 0; j < 4; ++j) {
                acc[i][j] = __builtin_amdgcn_mfma_f32_16x16x32_bf16(a0[i], b0[j], acc[i][j], 0, 0, 0);
                acc[i][j] = __builtin_amdgcn_mfma_f32_16x16x32_bf16(a1[i], b1[j], acc[i][j], 0, 0, 0);
            }
        __builtin_amdgcn_s_setprio(0);
        // tile T+1's loads were issued one full iteration ago -> this drain is cheap
        asm volatile("s_waitcnt vmcnt(0)" ::: "memory");
        __builtin_amdgcn_s_barrier();
        asm volatile("" ::: "memory");
        if (T + 2 < NT) STAGE2(buf);       // overwrite just-freed buffer with tile T+2
        buf ^= 1;
    }
#undef STAGE2

    float* Cout = Cpart + (size_t)ks * K2 * LTOT;
    int col = lane & 15, rq = (lane >> 4) * 4;
#pragma unroll
    for (int i = 0; i < 4; ++i) {
#pragma unroll
        for (int rr = 0; rr < 4; ++rr) {
            int m = bm + wm + i * 16 + rq + rr;
#pragma unroll
            for (int j = 0; j < 4; ++j)
                Cout[(size_t)m * LTOT + bn + wn + j * 16 + col] = acc[i][j][rr];
        }
    }
}

// ---------------- 9-tap patch stencil, 2-q PAIRED (q, q+1 same qy) ----------------
__global__ __launch_bounds__(256) void stencil_norm_kernel(
    const float* __restrict__ C, const float* __restrict__ invn,
    float* __restrict__ Sg)
{
    int blk = blockIdx.x;                    // 2048
    int h = ((blk & 7) << 8) | (blk >> 3);   // XCD swizzle: 256 contiguous pairs per XCD
    int q = h << 1;                          // even q; this block does q and q+1
    int t = threadIdx.x;
    int qy = q >> 6, qx = q & 63;            // qx even
    int chunk = t >> 2;                      // py (uniform over the 16 cols)
    int lanebase = (t & 3) << 4;             // px of first col
    int p0 = t << 4;

    f32x4 accA[4], accB[4];
#pragma unroll
    for (int g = 0; g < 4; ++g) {
        accA[g][0] = accA[g][1] = accA[g][2] = accA[g][3] = 0.f;
        accB[g][0] = accB[g][1] = accB[g][2] = accB[g][3] = 0.f;
    }

#pragma unroll
    for (int du = -1; du <= 1; ++du) {
        if (qy + du < 0 || qy + du > 63) continue;
        if (chunk + du < 0 || chunk + du > 63) continue;   // py+du (uniform)
#pragma unroll
        for (int dv = -1; dv <= 1; ++dv) {
            const float* rp = C + (size_t)(q + 64 * du + dv) * LTOT + 64 * du + dv + p0;
            if (qx + dv >= 0) {                            // A valid (upper bound always ok)
#pragma unroll
                for (int g = 0; g < 4; ++g) {
                    f32x4 lv = ld4u(rp + 4 * g);
                    if (dv == -1 && g == 0 && lanebase == 0)  lv[0] = 0.f;  // px+dv = -1
                    if (dv ==  1 && g == 3 && lanebase == 48) lv[3] = 0.f;  // px+dv = 64
                    accA[g] += lv;
                }
            }
            if (qx + 1 + dv <= 63) {                       // B valid (lower bound always ok)
                const float* rpB = rp + LTOT;
#pragma unroll
                for (int g = 0; g < 4; ++g) {
                    f32x4 lv = ld4u(rpB + 4 * g);
                    if (dv == -1 && g == 0 && lanebase == 0)  lv[0] = 0.f;
                    if (dv ==  1 && g == 3 && lanebase == 48) lv[3] = 0.f;
                    accB[g] += lv;
                }
            }
        }
    }
    {
        float* orow = Sg + (size_t)q * PSTR;
#pragma unroll
        for (int g = 0; g < 4; ++g) {
            f32x4 iv = *(const f32x4*)(invn + p0 + 4 * g);
            *(f32x4*)(orow + p0 + 4 * g) = accA[g] * iv;
        }
        if (t == 0) { orow[-4] = orow[-3] = orow[-2] = orow[-1] = 0.f; }
        else if (t == 1) { orow[4096] = orow[4097] = orow[4098] = orow[4099] = 0.f; }
    }
    {
        float* orow = Sg + (size_t)(q + 1) * PSTR;
#pragma unroll
        for (int g = 0; g < 4; ++g) {
            f32x4 iv = *(const f32x4*)(invn + p0 + 4 * g);
            *(f32x4*)(orow + p0 + 4 * g) = accB[g] * iv;
        }
        if (t == 2) { orow[-4] = orow[-3] = orow[-2] = orow[-1] = 0.f; }
        else if (t == 3) { orow[4096] = orow[4097] = orow[4098] = orow[4099] = 0.f; }
    }
    // zero guard rows -1 and 4096 (full padded rows)
    if (q == 0) {
        float* gr = Sg - 4 - PSTR;
        for (int k = t; k < PSTR; k += 256) gr[k] = 0.f;
    }
    if (q == 4094) {
        float* gr = Sg - 4 + (size_t)4096 * PSTR;
        for (int k = t; k < PSTR; k += 256) gr[k] = 0.f;
    }
}

// ---------------- fused (fuse2 o fuse1) stencil + row softmax + bf16, 2-q blocked (R9 win) ----------------
__global__ __launch_bounds__(256) void fused_conv_softmax_kernel(
    const float* __restrict__ Sg, const float* __restrict__ mmv,
    unsigned short* __restrict__ S16)
{
    __shared__ float redmax[8];
    __shared__ float redsum[8];
    int blk = blockIdx.x;                       // 2048
    int h = ((blk & 7) << 8) | (blk >> 3);      // XCD swizzle on pair index
    int qx = h & 63, qy2 = h >> 6;              // qy2 0..31
    int qA = (2 * qy2) * 64 + qx;               // sub0 (qy even)
    int qB = qA + 64;                           // sub1 (qy odd)
    int t = threadIdx.x;
    int lane = t & 63, wid = t >> 6;
    int chunk = t >> 2;
    int lanebase = (t & 3) << 4;
    int c0 = t << 4;

    int rbA = ((qA & 63) << 6) | (qA >> 6);     // swap(qA)
    int rbB = rbA + 1;                          // swap(qB) (qy odd, no field overflow)

    f32x4 sA[4], sB[4];
#pragma unroll
    for (int g = 0; g < 4; ++g) {
        sA[g][0] = sA[g][1] = sA[g][2] = sA[g][3] = 0.f;
        sB[g][0] = sB[g][1] = sB[g][2] = sB[g][3] = 0.f;
    }

#pragma unroll
    for (int j = 0; j < 3; ++j) {               // d2 = j-1
        int cj = chunk + (j - 1);
        int ccb;
        if (cj < 0)       ccb = 4031 + lanebase;
        else if (cj > 63) ccb = lanebase + 1;
        else              ccb = (cj << 6) + lanebase;

        int r2A = rbA + (j - 1);
        if (r2A >= 0 && r2A < LTOT) {
            int rr = ((r2A & 63) << 6) | ((r2A >> 6) & 63);
            const float* pr = Sg + (size_t)rr * PSTR + ccb;
#pragma unroll
            for (int g = 0; g < 4; ++g) {
                const float* pg = pr + 4 * g;
                f32x4 tj = ld4u(pg - (PSTR + 1)) + ld4u(pg) + ld4u(pg + (PSTR + 1));
                if (j == 0 && g == 0 && t == 0)   tj[0] = 0.f;   // c=0 corner
                if (j == 2 && g == 3 && t == 255) tj[3] = 0.f;   // c=4095 corner
                sA[g] += tj;
            }
        }
        int r2B = rbB + (j - 1);
        if (r2B >= 0 && r2B < LTOT) {
            int rr = ((r2B & 63) << 6) | ((r2B >> 6) & 63);
            const float* pr = Sg + (size_t)rr * PSTR + ccb;
#pragma unroll
            for (int g = 0; g < 4; ++g) {
                const float* pg = pr + 4 * g;
                f32x4 tj = ld4u(pg - (PSTR + 1)) + ld4u(pg) + ld4u(pg + (PSTR + 1));
                if (j == 0 && g == 0 && t == 0)   tj[0] = 0.f;
                if (j == 2 && g == 3 && t == 255) tj[3] = 0.f;
                sB[g] += tj;
            }
        }
    }

    float vA[16], vB[16];
#pragma unroll
    for (int g = 0; g < 4; ++g) {
        f32x4 m4 = *(const f32x4*)(mmv + c0 + 4 * g);
#pragma unroll
        for (int e = 0; e < 4; ++e) {
            vA[4 * g + e] = sA[g][e] * m4[e] * SCALE_F;
            vB[4 * g + e] = sB[g][e] * m4[e] * SCALE_F;
        }
    }
#pragma unroll
    for (int k = 0; k < 16; ++k) { asm volatile("" : "+v"(vA[k])); asm volatile("" : "+v"(vB[k])); }

    float mxA = vA[0], mxB = vB[0];
#pragma unroll
    for (int i = 1; i < 16; ++i) { mxA = fmaxf(mxA, vA[i]); mxB = fmaxf(mxB, vB[i]); }
#pragma unroll
    for (int o = 32; o; o >>= 1) { mxA = fmaxf(mxA, __shfl_xor(mxA, o)); mxB = fmaxf(mxB, __shfl_xor(mxB, o)); }
    if (lane == 0) { redmax[wid] = mxA; redmax[4 + wid] = mxB; }
    __syncthreads();
    float gmxA = fmaxf(fmaxf(redmax[0], redmax[1]), fmaxf(redmax[2], redmax[3]));
    float gmxB = fmaxf(fmaxf(redmax[4], redmax[5]), fmaxf(redmax[6], redmax[7]));

    float suA = 0.f, suB = 0.f;
#pragma unroll
    for (int i = 0; i < 16; ++i) {
        vA[i] = __expf(vA[i] - gmxA); suA += vA[i];
        vB[i] = __expf(vB[i] - gmxB); suB += vB[i];
    }
#pragma unroll
    for (int o = 32; o; o >>= 1) { suA += __shfl_xor(suA, o); suB += __shfl_xor(suB, o); }
    if (lane == 0) { redsum[wid] = suA; redsum[4 + wid] = suB; }
    __syncthreads();
    float invA = 1.f / (redsum[0] + redsum[1] + redsum[2] + redsum[3]);
    float invB = 1.f / (redsum[4] + redsum[5] + redsum[6] + redsum[7]);

    unsigned short* orowA = S16 + (size_t)qA * LTOT + c0;
    unsigned short* orowB = S16 + (size_t)qB * LTOT + c0;
    short8 hA0, hA1, hB0, hB1;
#pragma unroll
    for (int e = 0; e < 8; ++e) {
        float m0 = mmv[c0 + e], m1 = mmv[c0 + 8 + e];
        hA0[e] = (short)f2bf(vA[e]     * invA * m0);
        hA1[e] = (short)f2bf(vA[8 + e] * invA * m1);
        hB0[e] = (short)f2bf(vB[e]     * invB * m0);
        hB1[e] = (short)f2bf(vB[8 + e] * invB * m1);
    }
    *(short8*)orowA = hA0; *(short8*)(orowA + 8) = hA1;
    *(short8*)orowB = hB0; *(short8*)(orowB + 8) = hB1;
}

// ---------------- overlap-add of weighted 4x4 patches (stride 2), /4 — 2x2 OUTPUT TILE ----------------
__global__ void output_kernel(const float* __restrict__ C2t, float* __restrict__ out) {
    const float* __restrict__ P1 = C2t + (size_t)K2 * LTOT;
    int idx = blockIdx.x * blockDim.x + threadIdx.x;   // c*4096 + a*64 + b
    int b = idx & 63;
    int a = (idx >> 6) & 63;
    int c = idx >> 12;
#pragma unroll
    for (int dy = 0; dy < 2; ++dy) {
        int y = 2 * a + dy;
        float r[2];
#pragma unroll
        for (int dx = 0; dx < 2; ++dx) {
            int x = 2 * b + dx;
            int oylo = max(0, (y - 1) >> 1), oyhi = min(63, (y + 1) >> 1);
            int oxlo = max(0, (x - 1) >> 1), oxhi = min(63, (x + 1) >> 1);
            float s = 0.f;
            for (int oy = oylo; oy <= oyhi; ++oy)
                for (int ox = oxlo; ox <= oxhi; ++ox) {
                    int kd = y - 2 * oy + 1;
                    int ke = x - 2 * ox + 1;
                    size_t off = (size_t)(c * 16 + kd * 4 + ke) * LTOT + oy * 64 + ox;
                    s += C2t[off] + P1[off];
                }
            r[dx] = s * 0.25f;
        }
        f32x2 w; w[0] = r[0]; w[1] = r[1];
        *(f32x2*)(out + ((size_t)c * HH + y) * WW + 2 * b) = w;
    }
}

extern "C" void kernel_launch(void* const* d_in, const int* in_sizes, int n_in,
                              void* d_out, int out_size, void* d_ws, size_t ws_size,
                              hipStream_t stream) {
    (void)in_sizes; (void)n_in; (void)out_size; (void)ws_size;
    const float* f    = (const float*)d_in[0];
    const float* b    = (const float*)d_in[1];
    const float* mask = (const float*)d_in[2];
    float* out = (float*)d_out;

    const size_t SZ_MAT  = (size_t)LTOT * LTOT * 4;        // 64 MB
    const size_t SZ_SPAD = (size_t)PSTR * 4098 * 4;        // 67.3 MB padded S (guards + col pads)
    const size_t SZ_WR   = (size_t)K2 * LTOT * 2;          // 16 MB
    const size_t SZ_SP   = (size_t)LTOT * K0S * 2;         // 3 MB
    const size_t SZ_V    = (size_t)LTOT * 4;

    auto pad = [](size_t n) { return (n + 255) & ~(size_t)255; };
    char* p = (char*)d_ws;
    auto take = [&](size_t n) -> void* { void* r = (void*)p; p += pad(n); return r; };

    // footprint: 0.25K guard + 64 + 67.3 + 16 (single W) + 4*3 + small ~= 160 MB (< proven 172)
    take(256);                                     // guard: stencil corner reads C[-1]
    float* Buf1 = (float*)take(SZ_MAT);            // Cpix -> S16 (lower 32 MB)
    float* Spad = (float*)take(SZ_SPAD);           // padded S -> C2t partials (lower 64 MB)
    unsigned short* W = (unsigned short*)take(SZ_WR);   // per-batch raw patches (im2col in loop)
    unsigned short* Bsp0 = (unsigned short*)take(SZ_SP);
    unsigned short* Fsp0 = (unsigned short*)take(SZ_SP);
    unsigned short* Bsp1 = (unsigned short*)take(SZ_SP);
    unsigned short* Fsp1 = (unsigned short*)take(SZ_SP);
    float* ssq0 = (float*)take(SZ_V);  float* ssq1 = (float*)take(SZ_V);
    float* invn0 = (float*)take(SZ_V); float* invn1 = (float*)take(SZ_V);
    float* mmv0 = (float*)take(SZ_V);  float* mmv1 = (float*)take(SZ_V);

    const float* f0 = f,  *b0 = b;
    const float* f1 = f + IMG, *b1 = b + IMG;

    float* Sg = Spad + PSTR + 4;                   // padded S row 0, col 0
    unsigned short* S16 = (unsigned short*)Buf1;   // 32 MB, after Cpix dead
    float* C2t = Spad;                             // 2 x 32 MB partials, after padded S dead

    // ---- merged prep (both batches); ssq fused into the b split passes ----
    Prep4 P{{b0, f0, b1, f1}, {Bsp0, Fsp0, Bsp1, Fsp1},
            {ssq0, nullptr, ssq1, nullptr}, {1, 0, 1, 0}};
    split_ds_kernel<<<dim3(LTOT, 1, 4), 128, 0, stream>>>(P);
    PtrN2 nm{{ssq0, ssq1}, {invn0, invn1}, {mmv0, mmv1}};
    norm_mm_kernel<<<dim3(16, 1, 2), 256, 0, stream>>>(nm, mask);

    // ---- per-batch pipeline ----
    for (int bi = 0; bi < 2; ++bi) {
        const unsigned short* Fsp = bi ? Fsp1 : Fsp0;
        const unsigned short* Bsp = bi ? Bsp1 : Bsp0;
        const float* invn = bi ? invn1 : invn0;
        const float* mmv  = bi ? mmv1 : mmv0;

        // raw 4x4 patches for this batch only (W reused across batches); px-pair threads
        PtrR2 rw{{bi ? b1 : b0, nullptr}, {W, nullptr}};
        im2col_rawt_kernel<<<dim3((size_t)K2 * LTOT / 2 / 256, 1, 1), 256, 0, stream>>>(rw);

        // Cpix[q][p] = sum_c fd[c][q]*bd[c][p]   (split-concat fp32-accurate, K=384)
        gemm_mfma<<<dim3(32, 32), 256, 0, stream>>>(Fsp, Bsp, Buf1, LTOT, LTOT, K0S);

        // patch inner products: 9-tap diagonal stencil + invn column scale -> padded S (2-q pairs)
        stencil_norm_kernel<<<2048, 256, 0, stream>>>(Buf1, invn, Sg);

        // fused (fuse2 o fuse1) + softmax + bf16 cast  (2-q blocks; Cpix dead -> S16 in Buf1)
        fused_conv_softmax_kernel<<<2048, 256, 0, stream>>>(Sg, mmv, S16);

        // TRANSPOSED GEMM2 (128^2 ring-2, 2 blocks/CU): C2t_ks[m2][q] = sum_p W[m2][p]*S16[q][p]
        gemm_k2<<<1024, 256, 0, stream>>>(W, S16, C2t);

        // overlap-add, 2x2 output tile per thread
        output_kernel<<<CC * HH * WW / 4 / 256, 256, 0, stream>>>(C2t, out + (size_t)bi * IMG);
    }
}

// Round 13
// 486.911 us; speedup vs baseline: 1.1290x; 1.0160x over previous
//
#include <hip/hip_runtime.h>

#define CC 128
#define HH 128
#define WW 128
#define DH 64
#define DW 64
#define LTOT 4096          // DH*DW patches / fg positions
#define K0S 384            // 3*128 split-concat K for the pixel-pair GEMM
#define K2 2048            // CC*4*4
#define GK 4096            // GEMM2 full K
#define SCALE_F 10.0f
#define IMG ((size_t)CC * HH * WW)
#define PSTR 4104          // padded S row stride (floats): 4 pad | 4096 | 4 pad; %4==0 keeps 16B align

typedef __attribute__((ext_vector_type(8))) short short8;
typedef __attribute__((ext_vector_type(4))) float f32x4;
typedef __attribute__((ext_vector_type(2))) float f32x2;

// ---- pointer-pack structs (batch-merged prep via blockIdx.z) ----
struct Prep4 { const float* src[4]; unsigned short* dst[4]; float* ssq[4]; int lo[4]; };
struct PtrN2 { const float* ssq[2]; float* invn[2]; float* mmv[2]; };
struct PtrR2 { const float* src[2]; unsigned short* dst[2]; };

// ---- bf16 helpers (RNE) ----
__device__ __forceinline__ unsigned short f2bf(float x) {
    union { float f; unsigned u; } v; v.f = x;
    unsigned r = v.u + 0x7fffu + ((v.u >> 16) & 1u);
    return (unsigned short)(r >> 16);
}
__device__ __forceinline__ float bf2f(unsigned short b) {
    union { unsigned u; float f; } v; v.u = ((unsigned)b) << 16;
    return v.f;
}

// unaligned (4B-aligned) float4 load
__device__ __forceinline__ f32x4 ld4u(const float* p) {
    f32x4 r; __builtin_memcpy(&r, p, 16); return r;
}

#define GLDS16(g, l) __builtin_amdgcn_global_load_lds( \
    (const __attribute__((address_space(1))) void*)(g), \
    (__attribute__((address_space(3))) void*)(l), 16, 0, 0)

// ---------------- downsample (::2) + fp32->bf16 split + (for b) fused ssq reduce ----------------
// b gets [hi, lo, hi], f gets [hi, hi, lo]  =>  products sum to hi*hi + lo*hi + hi*lo
__global__ __launch_bounds__(128) void split_ds_kernel(Prep4 P) {
    __shared__ float partial[2];
    int z = blockIdx.z;
    const float* __restrict__ src = P.src[z];
    unsigned short* __restrict__ dst = P.dst[z];
    int lo_in_seg1 = P.lo[z];
    int n = blockIdx.x;          // 4096 pixels
    int c = threadIdx.x;         // 128 channels
    int ny = n >> 6, nx = n & 63;
    float v = src[((size_t)c * HH + 2 * ny) * WW + 2 * nx];
    unsigned short hi = f2bf(v);
    unsigned short lo = f2bf(v - bf2f(hi));
    unsigned short* drow = dst + (size_t)n * K0S;
    drow[c]       = hi;
    drow[128 + c] = lo_in_seg1 ? lo : hi;
    drow[256 + c] = lo_in_seg1 ? hi : lo;

    float* ssq = P.ssq[z];
    if (ssq) {                   // b images only: per-pixel channel sum of squares
        float s2 = v * v;
#pragma unroll
        for (int o = 32; o; o >>= 1) s2 += __shfl_xor(s2, o);
        if ((threadIdx.x & 63) == 0) partial[threadIdx.x >> 6] = s2;
        __syncthreads();
        if (threadIdx.x == 0) ssq[n] = partial[0] + partial[1];
    }
}

// ---------------- raw 4x4 stride-2 patches of full-res b, transposed: dst[m2][p] bf16 ----------------
// R8: thread owns a px-PAIR; interior threads cover both taps with one unaligned f32x4.
__global__ __launch_bounds__(256) void im2col_rawt_kernel(PtrR2 P) {
    int z = blockIdx.z;
    const float* __restrict__ src = P.src[z];
    unsigned short* __restrict__ dst = P.dst[z];
    int idx = blockIdx.x * 256 + threadIdx.x;     // m*2048 + py*32 + u
    int u  = idx & 31;                             // px pair index: px0 = 2u
    int py = (idx >> 5) & 63;
    int m  = idx >> 11;                            // (c,kd,ke)
    int ke = m & 3, kd = (m >> 2) & 3, c = m >> 4;
    int yy = 2 * py - 1 + kd;
    int xx0 = 4 * u - 1 + ke;                      // xx for px0; px1 uses xx0+2
    unsigned short o0 = 0, o1 = 0;
    if (yy >= 0 && yy < HH) {
        const float* row = src + ((size_t)c * HH + yy) * WW;
        if (u == 0 || u == 31) {                   // edges: scalar, bounds-checked
            if (xx0 >= 0 && xx0 < WW)         o0 = f2bf(row[xx0]);
            if (xx0 + 2 >= 0 && xx0 + 2 < WW) o1 = f2bf(row[xx0 + 2]);
        } else {                                   // interior: xx0 in [3,122]
            f32x4 w = ld4u(row + xx0);
            o0 = f2bf(w[0]); o1 = f2bf(w[2]);
        }
    }
    unsigned short* dp = dst + (size_t)m * LTOT + py * 64 + 2 * u;
    dp[0] = o0; dp[1] = o1;
}

// ---------------- patch inverse norm + mask gate ----------------
__global__ void norm_mm_kernel(PtrN2 P, const float* __restrict__ mask) {
    int z = blockIdx.z;
    const float* __restrict__ ssq = P.ssq[z];
    float* __restrict__ inv_norm = P.invn[z];
    float* __restrict__ mmv = P.mmv[z];
    int p = blockIdx.x * blockDim.x + threadIdx.x;     // 4096
    int px = p & 63, py = p >> 6;
    float s = 0.f, ms = 0.f;
    for (int di = -1; di <= 1; ++di)
        for (int dj = -1; dj <= 1; ++dj) {
            int y = py + di, x = px + dj;
            if (y >= 0 && y < DH && x >= 0 && x < DW) {
                s += ssq[y * 64 + x];
                ms += mask[(size_t)(2 * y) * WW + 2 * x];
            }
        }
    float n = sqrtf(s);
    if (n < 1e-4f) n = 1e-4f;
    inv_norm[p] = 1.f / n;
    mmv[p] = (ms == 0.f) ? 1.f : 0.f;
}

// ---------------- bf16 MFMA GEMM, BK=64, hoisted running pointers, XOR swizzle ----------------
// (kept for GEMM1: M=N=4096, K=384 — short-K, 1024 blocks; operands 3MB+3MB L3-resident)
__global__ __launch_bounds__(256) void gemm_mfma(
    const unsigned short* __restrict__ Aop, const unsigned short* __restrict__ Bop,
    float* __restrict__ C, int M, int N, int K)
{
    __shared__ short As[128 * 64];
    __shared__ short Bs[128 * 64];
    int tid = threadIdx.x;
    int wave = tid >> 6, lane = tid & 63;
    int wm = (wave >> 1) * 64;
    int wn = (wave & 1) * 64;
    int bm = blockIdx.y * 128, bn = blockIdx.x * 128;

    int rowS = wave * 32;              // wave stages rows [rowS, rowS+32)
    int lrow8 = lane >> 3;             // 0..7 (row within 8-row staging group)
    int gchunk = ((lane & 7) ^ lrow8) * 8;   // swizzled global k-offset (shorts)

    f32x4 acc[4][4] = {};

    int quad = lane >> 4;              // 0..3
    int r16 = lane & 15;
    int pc0 = ((quad)     ^ (r16 & 7)) * 8;  // physical chunk of k-slab 0
    int pc1 = ((4 + quad) ^ (r16 & 7)) * 8;  // physical chunk of k-slab 1

    const unsigned short* ap0 = Aop + (size_t)(bm + rowS +  0 + lrow8) * K + gchunk;
    const unsigned short* ap1 = Aop + (size_t)(bm + rowS +  8 + lrow8) * K + gchunk;
    const unsigned short* ap2 = Aop + (size_t)(bm + rowS + 16 + lrow8) * K + gchunk;
    const unsigned short* ap3 = Aop + (size_t)(bm + rowS + 24 + lrow8) * K + gchunk;
    const unsigned short* bp0 = Bop + (size_t)(bn + rowS +  0 + lrow8) * K + gchunk;
    const unsigned short* bp1 = Bop + (size_t)(bn + rowS +  8 + lrow8) * K + gchunk;
    const unsigned short* bp2 = Bop + (size_t)(bn + rowS + 16 + lrow8) * K + gchunk;
    const unsigned short* bp3 = Bop + (size_t)(bn + rowS + 24 + lrow8) * K + gchunk;
    short* lA = As + rowS * 64;        // wave-uniform LDS bases
    short* lB = Bs + rowS * 64;

    for (int k0 = 0; k0 < K; k0 += 64) {
        GLDS16(ap0, lA);            GLDS16(ap1, lA + 8 * 64);
        GLDS16(ap2, lA + 16 * 64);  GLDS16(ap3, lA + 24 * 64);
        GLDS16(bp0, lB);            GLDS16(bp1, lB + 8 * 64);
        GLDS16(bp2, lB + 16 * 64);  GLDS16(bp3, lB + 24 * 64);
        ap0 += 64; ap1 += 64; ap2 += 64; ap3 += 64;
        bp0 += 64; bp1 += 64; bp2 += 64; bp3 += 64;
        __syncthreads();

        short8 a0[4], b0[4], a1[4], b1[4];
#pragma unroll
        for (int i = 0; i < 4; ++i) {
            a0[i] = *(const short8*)&As[(wm + i * 16 + r16) * 64 + pc0];
            b0[i] = *(const short8*)&Bs[(wn + i * 16 + r16) * 64 + pc0];
            a1[i] = *(const short8*)&As[(wm + i * 16 + r16) * 64 + pc1];
            b1[i] = *(const short8*)&Bs[(wn + i * 16 + r16) * 64 + pc1];
        }
#pragma unroll
        for (int i = 0; i < 4; ++i)
#pragma unroll
            for (int j = 0; j < 4; ++j) {
                acc[i][j] = __builtin_amdgcn_mfma_f32_16x16x32_bf16(a0[i], b0[j], acc[i][j], 0, 0, 0);
                acc[i][j] = __builtin_amdgcn_mfma_f32_16x16x32_bf16(a1[i], b1[j], acc[i][j], 0, 0, 0);
            }
        __syncthreads();
    }

    int col = lane & 15, rq = (lane >> 4) * 4;
#pragma unroll
    for (int i = 0; i < 4; ++i) {
#pragma unroll
        for (int r = 0; r < 4; ++r) {
            int m = bm + wm + i * 16 + rq + r;
#pragma unroll
            for (int j = 0; j < 4; ++j)
                C[(size_t)m * N + bn + wn + j * 16 + col] = acc[i][j][r];
        }
    }
}

// ---------------- GEMM2: 128x128 tile, FULL-K (no split), ring-2 counted vmcnt, 2 BLOCKS/CU ----------------
// R13: with 128^2 tiles the natural grid (32 bn x 16 bm = 512 blocks) is already 2/CU —
// split-K (R5's fix for 256^2's half-grid) is dead weight here: it doubled C-writes
// (64 MB of partials) + doubled output_kernel reads + halved K-per-block. Dropped.
// One fp32 accumulation chain over K=4096 (R3's proven pattern). XCD grouping: 4 bn-panels
// per XCD, each B-panel read by 16 same-XCD bm-blocks. 2 blocks/CU (64 KB LDS) for
// cross-block MFMA/LDS overlap (R12's proven +3%).
__global__ __launch_bounds__(256, 2) void gemm_k2(
    const unsigned short* __restrict__ Aop, const unsigned short* __restrict__ Bop,
    float* __restrict__ Cout)
{
    constexpr int NT = 64;                    // GK / 64
    constexpr int BUFS = 256 * 64;            // shorts per ring slot (32 KB: A[128][64]+B[128][64])
    __shared__ short lds[2 * BUFS];           // 64 KB -> 2 blocks/CU
    int flat = blockIdx.x;                    // 512
    int xcd  = flat & 7;
    int r    = flat >> 3;                     // 0..63
    int bnId = xcd * 4 + (r & 3);             // 0..31 (4 bn-panels per XCD)
    int bmId = r >> 2;                        // 0..15
    int bm = bmId * 128, bn = bnId * 128;

    int tid = threadIdx.x;
    int wave = tid >> 6, lane = tid & 63;
    int wm = (wave >> 1) * 64;
    int wn = (wave & 1) * 64;
    int rowS = wave * 32;                     // wave stages rows [rowS, rowS+32) of A and B
    int lrow8 = lane >> 3;
    int gchunk = ((lane & 7) ^ lrow8) * 8;    // pre-swizzled global k-offset (shorts)
    int r16 = lane & 15, quad = lane >> 4;
    int pc0 = ((quad)     ^ (r16 & 7)) * 8;
    int pc1 = ((4 + quad) ^ (r16 & 7)) * 8;

    const unsigned short* ap0 = Aop + (size_t)(bm + rowS +  0 + lrow8) * GK + gchunk;
    const unsigned short* ap1 = Aop + (size_t)(bm + rowS +  8 + lrow8) * GK + gchunk;
    const unsigned short* ap2 = Aop + (size_t)(bm + rowS + 16 + lrow8) * GK + gchunk;
    const unsigned short* ap3 = Aop + (size_t)(bm + rowS + 24 + lrow8) * GK + gchunk;
    const unsigned short* bp0 = Bop + (size_t)(bn + rowS +  0 + lrow8) * GK + gchunk;
    const unsigned short* bp1 = Bop + (size_t)(bn + rowS +  8 + lrow8) * GK + gchunk;
    const unsigned short* bp2 = Bop + (size_t)(bn + rowS + 16 + lrow8) * GK + gchunk;
    const unsigned short* bp3 = Bop + (size_t)(bn + rowS + 24 + lrow8) * GK + gchunk;

    f32x4 acc[4][4] = {};

#define STAGE2(s) do { \
    short* la = lds + (s) * BUFS + rowS * 64; \
    short* lb = lds + (s) * BUFS + 128 * 64 + rowS * 64; \
    GLDS16(ap0, la);            GLDS16(ap1, la + 8 * 64); \
    GLDS16(ap2, la + 16 * 64);  GLDS16(ap3, la + 24 * 64); \
    GLDS16(bp0, lb);            GLDS16(bp1, lb + 8 * 64); \
    GLDS16(bp2, lb + 16 * 64);  GLDS16(bp3, lb + 24 * 64); \
    ap0 += 64; ap1 += 64; ap2 += 64; ap3 += 64; \
    bp0 += 64; bp1 += 64; bp2 += 64; bp3 += 64; } while (0)

    // prologue: tiles 0,1; require tile 0 resident (tile 1's 8 loads stay in flight)
    STAGE2(0); STAGE2(1);
    asm volatile("s_waitcnt vmcnt(8)" ::: "memory");
    __builtin_amdgcn_s_barrier();
    asm volatile("" ::: "memory");

    int buf = 0;
#pragma unroll 1
    for (int T = 0; T < NT; ++T) {
        const short* Ab = lds + buf * BUFS;
        const short* Bb = Ab + 128 * 64;
        short8 a0[4], a1[4], b0[4], b1[4];
#pragma unroll
        for (int i = 0; i < 4; ++i) {
            a0[i] = *(const short8*)&Ab[(wm + i * 16 + r16) * 64 + pc0];
            a1[i] = *(const short8*)&Ab[(wm + i * 16 + r16) * 64 + pc1];
            b0[i] = *(const short8*)&Bb[(wn + i * 16 + r16) * 64 + pc0];
            b1[i] = *(const short8*)&Bb[(wn + i * 16 + r16) * 64 + pc1];
        }
        asm volatile("s_waitcnt lgkmcnt(0)" ::: "memory");
        __builtin_amdgcn_sched_barrier(0);                 // rule 18: pin MFMA below wait
        __builtin_amdgcn_s_setprio(1);
#pragma unroll
        for (int i = 0; i < 4; ++i)
#pragma unroll
            for (int j = 0; j < 4; ++j) {
                acc[i][j] = __builtin_amdgcn_mfma_f32_16x16x32_bf16(a0[i], b0[j], acc[i][j], 0, 0, 0);
                acc[i][j] = __builtin_amdgcn_mfma_f32_16x16x32_bf16(a1[i], b1[j], acc[i][j], 0, 0, 0);
            }
        __builtin_amdgcn_s_setprio(0);
        // tile T+1's loads were issued one full iteration ago -> this drain is cheap
        asm volatile("s_waitcnt vmcnt(0)" ::: "memory");
        __builtin_amdgcn_s_barrier();
        asm volatile("" ::: "memory");
        if (T + 2 < NT) STAGE2(buf);       // overwrite just-freed buffer with tile T+2
        buf ^= 1;
    }
#undef STAGE2

    int col = lane & 15, rq = (lane >> 4) * 4;
#pragma unroll
    for (int i = 0; i < 4; ++i) {
#pragma unroll
        for (int rr = 0; rr < 4; ++rr) {
            int m = bm + wm + i * 16 + rq + rr;
#pragma unroll
            for (int j = 0; j < 4; ++j)
                Cout[(size_t)m * LTOT + bn + wn + j * 16 + col] = acc[i][j][rr];
        }
    }
}

// ---------------- 9-tap patch stencil, 2-q PAIRED (q, q+1 same qy) ----------------
__global__ __launch_bounds__(256) void stencil_norm_kernel(
    const float* __restrict__ C, const float* __restrict__ invn,
    float* __restrict__ Sg)
{
    int blk = blockIdx.x;                    // 2048
    int h = ((blk & 7) << 8) | (blk >> 3);   // XCD swizzle: 256 contiguous pairs per XCD
    int q = h << 1;                          // even q; this block does q and q+1
    int t = threadIdx.x;
    int qy = q >> 6, qx = q & 63;            // qx even
    int chunk = t >> 2;                      // py (uniform over the 16 cols)
    int lanebase = (t & 3) << 4;             // px of first col
    int p0 = t << 4;

    f32x4 accA[4], accB[4];
#pragma unroll
    for (int g = 0; g < 4; ++g) {
        accA[g][0] = accA[g][1] = accA[g][2] = accA[g][3] = 0.f;
        accB[g][0] = accB[g][1] = accB[g][2] = accB[g][3] = 0.f;
    }

#pragma unroll
    for (int du = -1; du <= 1; ++du) {
        if (qy + du < 0 || qy + du > 63) continue;
        if (chunk + du < 0 || chunk + du > 63) continue;   // py+du (uniform)
#pragma unroll
        for (int dv = -1; dv <= 1; ++dv) {
            const float* rp = C + (size_t)(q + 64 * du + dv) * LTOT + 64 * du + dv + p0;
            if (qx + dv >= 0) {                            // A valid (upper bound always ok)
#pragma unroll
                for (int g = 0; g < 4; ++g) {
                    f32x4 lv = ld4u(rp + 4 * g);
                    if (dv == -1 && g == 0 && lanebase == 0)  lv[0] = 0.f;  // px+dv = -1
                    if (dv ==  1 && g == 3 && lanebase == 48) lv[3] = 0.f;  // px+dv = 64
                    accA[g] += lv;
                }
            }
            if (qx + 1 + dv <= 63) {                       // B valid (lower bound always ok)
                const float* rpB = rp + LTOT;
#pragma unroll
                for (int g = 0; g < 4; ++g) {
                    f32x4 lv = ld4u(rpB + 4 * g);
                    if (dv == -1 && g == 0 && lanebase == 0)  lv[0] = 0.f;
                    if (dv ==  1 && g == 3 && lanebase == 48) lv[3] = 0.f;
                    accB[g] += lv;
                }
            }
        }
    }
    {
        float* orow = Sg + (size_t)q * PSTR;
#pragma unroll
        for (int g = 0; g < 4; ++g) {
            f32x4 iv = *(const f32x4*)(invn + p0 + 4 * g);
            *(f32x4*)(orow + p0 + 4 * g) = accA[g] * iv;
        }
        if (t == 0) { orow[-4] = orow[-3] = orow[-2] = orow[-1] = 0.f; }
        else if (t == 1) { orow[4096] = orow[4097] = orow[4098] = orow[4099] = 0.f; }
    }
    {
        float* orow = Sg + (size_t)(q + 1) * PSTR;
#pragma unroll
        for (int g = 0; g < 4; ++g) {
            f32x4 iv = *(const f32x4*)(invn + p0 + 4 * g);
            *(f32x4*)(orow + p0 + 4 * g) = accB[g] * iv;
        }
        if (t == 2) { orow[-4] = orow[-3] = orow[-2] = orow[-1] = 0.f; }
        else if (t == 3) { orow[4096] = orow[4097] = orow[4098] = orow[4099] = 0.f; }
    }
    // zero guard rows -1 and 4096 (full padded rows)
    if (q == 0) {
        float* gr = Sg - 4 - PSTR;
        for (int k = t; k < PSTR; k += 256) gr[k] = 0.f;
    }
    if (q == 4094) {
        float* gr = Sg - 4 + (size_t)4096 * PSTR;
        for (int k = t; k < PSTR; k += 256) gr[k] = 0.f;
    }
}

// ---------------- fused (fuse2 o fuse1) stencil + row softmax + bf16, 2-q blocked (R9 win) ----------------
__global__ __launch_bounds__(256) void fused_conv_softmax_kernel(
    const float* __restrict__ Sg, const float* __restrict__ mmv,
    unsigned short* __restrict__ S16)
{
    __shared__ float redmax[8];
    __shared__ float redsum[8];
    int blk = blockIdx.x;                       // 2048
    int h = ((blk & 7) << 8) | (blk >> 3);      // XCD swizzle on pair index
    int qx = h & 63, qy2 = h >> 6;              // qy2 0..31
    int qA = (2 * qy2) * 64 + qx;               // sub0 (qy even)
    int qB = qA + 64;                           // sub1 (qy odd)
    int t = threadIdx.x;
    int lane = t & 63, wid = t >> 6;
    int chunk = t >> 2;
    int lanebase = (t & 3) << 4;
    int c0 = t << 4;

    int rbA = ((qA & 63) << 6) | (qA >> 6);     // swap(qA)
    int rbB = rbA + 1;                          // swap(qB) (qy odd, no field overflow)

    f32x4 sA[4], sB[4];
#pragma unroll
    for (int g = 0; g < 4; ++g) {
        sA[g][0] = sA[g][1] = sA[g][2] = sA[g][3] = 0.f;
        sB[g][0] = sB[g][1] = sB[g][2] = sB[g][3] = 0.f;
    }

#pragma unroll
    for (int j = 0; j < 3; ++j) {               // d2 = j-1
        int cj = chunk + (j - 1);
        int ccb;
        if (cj < 0)       ccb = 4031 + lanebase;
        else if (cj > 63) ccb = lanebase + 1;
        else              ccb = (cj << 6) + lanebase;

        int r2A = rbA + (j - 1);
        if (r2A >= 0 && r2A < LTOT) {
            int rr = ((r2A & 63) << 6) | ((r2A >> 6) & 63);
            const float* pr = Sg + (size_t)rr * PSTR + ccb;
#pragma unroll
            for (int g = 0; g < 4; ++g) {
                const float* pg = pr + 4 * g;
                f32x4 tj = ld4u(pg - (PSTR + 1)) + ld4u(pg) + ld4u(pg + (PSTR + 1));
                if (j == 0 && g == 0 && t == 0)   tj[0] = 0.f;   // c=0 corner
                if (j == 2 && g == 3 && t == 255) tj[3] = 0.f;   // c=4095 corner
                sA[g] += tj;
            }
        }
        int r2B = rbB + (j - 1);
        if (r2B >= 0 && r2B < LTOT) {
            int rr = ((r2B & 63) << 6) | ((r2B >> 6) & 63);
            const float* pr = Sg + (size_t)rr * PSTR + ccb;
#pragma unroll
            for (int g = 0; g < 4; ++g) {
                const float* pg = pr + 4 * g;
                f32x4 tj = ld4u(pg - (PSTR + 1)) + ld4u(pg) + ld4u(pg + (PSTR + 1));
                if (j == 0 && g == 0 && t == 0)   tj[0] = 0.f;
                if (j == 2 && g == 3 && t == 255) tj[3] = 0.f;
                sB[g] += tj;
            }
        }
    }

    float vA[16], vB[16];
#pragma unroll
    for (int g = 0; g < 4; ++g) {
        f32x4 m4 = *(const f32x4*)(mmv + c0 + 4 * g);
#pragma unroll
        for (int e = 0; e < 4; ++e) {
            vA[4 * g + e] = sA[g][e] * m4[e] * SCALE_F;
            vB[4 * g + e] = sB[g][e] * m4[e] * SCALE_F;
        }
    }
#pragma unroll
    for (int k = 0; k < 16; ++k) { asm volatile("" : "+v"(vA[k])); asm volatile("" : "+v"(vB[k])); }

    float mxA = vA[0], mxB = vB[0];
#pragma unroll
    for (int i = 1; i < 16; ++i) { mxA = fmaxf(mxA, vA[i]); mxB = fmaxf(mxB, vB[i]); }
#pragma unroll
    for (int o = 32; o; o >>= 1) { mxA = fmaxf(mxA, __shfl_xor(mxA, o)); mxB = fmaxf(mxB, __shfl_xor(mxB, o)); }
    if (lane == 0) { redmax[wid] = mxA; redmax[4 + wid] = mxB; }
    __syncthreads();
    float gmxA = fmaxf(fmaxf(redmax[0], redmax[1]), fmaxf(redmax[2], redmax[3]));
    float gmxB = fmaxf(fmaxf(redmax[4], redmax[5]), fmaxf(redmax[6], redmax[7]));

    float suA = 0.f, suB = 0.f;
#pragma unroll
    for (int i = 0; i < 16; ++i) {
        vA[i] = __expf(vA[i] - gmxA); suA += vA[i];
        vB[i] = __expf(vB[i] - gmxB); suB += vB[i];
    }
#pragma unroll
    for (int o = 32; o; o >>= 1) { suA += __shfl_xor(suA, o); suB += __shfl_xor(suB, o); }
    if (lane == 0) { redsum[wid] = suA; redsum[4 + wid] = suB; }
    __syncthreads();
    float invA = 1.f / (redsum[0] + redsum[1] + redsum[2] + redsum[3]);
    float invB = 1.f / (redsum[4] + redsum[5] + redsum[6] + redsum[7]);

    unsigned short* orowA = S16 + (size_t)qA * LTOT + c0;
    unsigned short* orowB = S16 + (size_t)qB * LTOT + c0;
    short8 hA0, hA1, hB0, hB1;
#pragma unroll
    for (int e = 0; e < 8; ++e) {
        float m0 = mmv[c0 + e], m1 = mmv[c0 + 8 + e];
        hA0[e] = (short)f2bf(vA[e]     * invA * m0);
        hA1[e] = (short)f2bf(vA[8 + e] * invA * m1);
        hB0[e] = (short)f2bf(vB[e]     * invB * m0);
        hB1[e] = (short)f2bf(vB[8 + e] * invB * m1);
    }
    *(short8*)orowA = hA0; *(short8*)(orowA + 8) = hA1;
    *(short8*)orowB = hB0; *(short8*)(orowB + 8) = hB1;
}

// ---------------- overlap-add of weighted 4x4 patches (stride 2), /4 — 2x2 OUTPUT TILE ----------------
// R13: single C2t buffer (split-K dropped) — reads halve vs R12.
__global__ void output_kernel(const float* __restrict__ C2t, float* __restrict__ out) {
    int idx = blockIdx.x * blockDim.x + threadIdx.x;   // c*4096 + a*64 + b
    int b = idx & 63;
    int a = (idx >> 6) & 63;
    int c = idx >> 12;
#pragma unroll
    for (int dy = 0; dy < 2; ++dy) {
        int y = 2 * a + dy;
        float r[2];
#pragma unroll
        for (int dx = 0; dx < 2; ++dx) {
            int x = 2 * b + dx;
            int oylo = max(0, (y - 1) >> 1), oyhi = min(63, (y + 1) >> 1);
            int oxlo = max(0, (x - 1) >> 1), oxhi = min(63, (x + 1) >> 1);
            float s = 0.f;
            for (int oy = oylo; oy <= oyhi; ++oy)
                for (int ox = oxlo; ox <= oxhi; ++ox) {
                    int kd = y - 2 * oy + 1;
                    int ke = x - 2 * ox + 1;
                    s += C2t[(size_t)(c * 16 + kd * 4 + ke) * LTOT + oy * 64 + ox];
                }
            r[dx] = s * 0.25f;
        }
        f32x2 w; w[0] = r[0]; w[1] = r[1];
        *(f32x2*)(out + ((size_t)c * HH + y) * WW + 2 * b) = w;
    }
}

extern "C" void kernel_launch(void* const* d_in, const int* in_sizes, int n_in,
                              void* d_out, int out_size, void* d_ws, size_t ws_size,
                              hipStream_t stream) {
    (void)in_sizes; (void)n_in; (void)out_size; (void)ws_size;
    const float* f    = (const float*)d_in[0];
    const float* b    = (const float*)d_in[1];
    const float* mask = (const float*)d_in[2];
    float* out = (float*)d_out;

    const size_t SZ_MAT  = (size_t)LTOT * LTOT * 4;        // 64 MB
    const size_t SZ_SPAD = (size_t)PSTR * 4098 * 4;        // 67.3 MB padded S (guards + col pads)
    const size_t SZ_WR   = (size_t)K2 * LTOT * 2;          // 16 MB
    const size_t SZ_SP   = (size_t)LTOT * K0S * 2;         // 3 MB
    const size_t SZ_V    = (size_t)LTOT * 4;

    auto pad = [](size_t n) { return (n + 255) & ~(size_t)255; };
    char* p = (char*)d_ws;
    auto take = [&](size_t n) -> void* { void* r = (void*)p; p += pad(n); return r; };

    // footprint: 0.25K guard + 64 + 67.3 + 16 (single W) + 4*3 + small ~= 160 MB (< proven 172)
    take(256);                                     // guard: stencil corner reads C[-1]
    float* Buf1 = (float*)take(SZ_MAT);            // Cpix -> S16 (lower 32 MB)
    float* Spad = (float*)take(SZ_SPAD);           // padded S -> C2t (lower 32 MB)
    unsigned short* W = (unsigned short*)take(SZ_WR);   // per-batch raw patches (im2col in loop)
    unsigned short* Bsp0 = (unsigned short*)take(SZ_SP);
    unsigned short* Fsp0 = (unsigned short*)take(SZ_SP);
    unsigned short* Bsp1 = (unsigned short*)take(SZ_SP);
    unsigned short* Fsp1 = (unsigned short*)take(SZ_SP);
    float* ssq0 = (float*)take(SZ_V);  float* ssq1 = (float*)take(SZ_V);
    float* invn0 = (float*)take(SZ_V); float* invn1 = (float*)take(SZ_V);
    float* mmv0 = (float*)take(SZ_V);  float* mmv1 = (float*)take(SZ_V);

    const float* f0 = f,  *b0 = b;
    const float* f1 = f + IMG, *b1 = b + IMG;

    float* Sg = Spad + PSTR + 4;                   // padded S row 0, col 0
    unsigned short* S16 = (unsigned short*)Buf1;   // 32 MB, after Cpix dead
    float* C2t = Spad;                             // 32 MB, after padded S dead

    // ---- merged prep (both batches); ssq fused into the b split passes ----
    Prep4 P{{b0, f0, b1, f1}, {Bsp0, Fsp0, Bsp1, Fsp1},
            {ssq0, nullptr, ssq1, nullptr}, {1, 0, 1, 0}};
    split_ds_kernel<<<dim3(LTOT, 1, 4), 128, 0, stream>>>(P);
    PtrN2 nm{{ssq0, ssq1}, {invn0, invn1}, {mmv0, mmv1}};
    norm_mm_kernel<<<dim3(16, 1, 2), 256, 0, stream>>>(nm, mask);

    // ---- per-batch pipeline ----
    for (int bi = 0; bi < 2; ++bi) {
        const unsigned short* Fsp = bi ? Fsp1 : Fsp0;
        const unsigned short* Bsp = bi ? Bsp1 : Bsp0;
        const float* invn = bi ? invn1 : invn0;
        const float* mmv  = bi ? mmv1 : mmv0;

        // raw 4x4 patches for this batch only (W reused across batches); px-pair threads
        PtrR2 rw{{bi ? b1 : b0, nullptr}, {W, nullptr}};
        im2col_rawt_kernel<<<dim3((size_t)K2 * LTOT / 2 / 256, 1, 1), 256, 0, stream>>>(rw);

        // Cpix[q][p] = sum_c fd[c][q]*bd[c][p]   (split-concat fp32-accurate, K=384)
        gemm_mfma<<<dim3(32, 32), 256, 0, stream>>>(Fsp, Bsp, Buf1, LTOT, LTOT, K0S);

        // patch inner products: 9-tap diagonal stencil + invn column scale -> padded S (2-q pairs)
        stencil_norm_kernel<<<2048, 256, 0, stream>>>(Buf1, invn, Sg);

        // fused (fuse2 o fuse1) + softmax + bf16 cast  (2-q blocks; Cpix dead -> S16 in Buf1)
        fused_conv_softmax_kernel<<<2048, 256, 0, stream>>>(Sg, mmv, S16);

        // TRANSPOSED GEMM2 (128^2 full-K ring-2, 2 blocks/CU): C2t[m2][q] = sum_p W[m2][p]*S16[q][p]
        gemm_k2<<<512, 256, 0, stream>>>(W, S16, C2t);

        // overlap-add, 2x2 output tile per thread (single buffer)
        output_kernel<<<CC * HH * WW / 4 / 256, 256, 0, stream>>>(C2t, out + (size_t)bi * IMG);
    }
}